// Round 12
// baseline (360.959 us; speedup 1.0000x reference)
//
#include <hip/hip_runtime.h>
#include <hip/hip_bf16.h>

#define NNODES 40000
#define NEDGES 640000
#define M2PAD  40064
#define HID    128
#define PADCAP 920064                 // >= NEDGES + 7*NNODES, multiple of 256

typedef __attribute__((ext_vector_type(8))) short bf16x8;
typedef __attribute__((ext_vector_type(4))) float f32x4;

__device__ __forceinline__ float bl(unsigned u){ return __uint_as_float(u << 16); }
__device__ __forceinline__ float bh(unsigned u){ return __uint_as_float(u & 0xFFFF0000u); }
__device__ __forceinline__ unsigned short f2b(float f){
    unsigned u = __float_as_uint(f);
    u = (u + 0x7FFFu + ((u >> 16) & 1u)) >> 16;   // round-to-nearest-even
    return (unsigned short)u;
}
__device__ __forceinline__ float fast_rcp(float x){ return __builtin_amdgcn_rcpf(x); }

__device__ __forceinline__ void g2l16(const void* g, void* l){
    __builtin_amdgcn_global_load_lds(
        (const __attribute__((address_space(1))) unsigned int*)g,
        (__attribute__((address_space(3))) unsigned int*)l, 16, 0, 0);
}

// edge weight: lrelu(el+er) -> exp, zero for pad slots (j >= remaining real edges)
__device__ __forceinline__ float wcalc(float e, float erw, int j, int rem){
    float t = e + erw;
    t = (t > 0.f) ? t : 0.2f * t;
    t = __expf(t);
    return (j < rem) ? t : 0.f;
}

// LDS byte offset for bf16 element (row, col) in the XOR-swizzled A layout the
// MFMA fragment reader uses: chunk (col>>3) xor'd with (row&15), 2B within chunk.
__device__ __forceinline__ unsigned lds_off(int row, int col){
    return (unsigned)(row * 256 + (((col >> 3) ^ (row & 15)) << 4) + ((col & 7) << 1));
}

// ---------- prep: nf convert (0..4999) + transpose (5000..5255) + gru cvt (5256..5447)
//            + degree count into 8 planes (5448..7947) ----------
__global__ void prep_all(const float* __restrict__ node_feats,
                         const float* __restrict__ proj_W, const float* __restrict__ fc_W,
                         const float* __restrict__ gru_Wih, const int* __restrict__ dstp,
                         unsigned short* __restrict__ nf,
                         unsigned short* __restrict__ projWT, unsigned short* __restrict__ fcWT,
                         unsigned short* __restrict__ gruWb, int* __restrict__ deg8){
    int b = blockIdx.x;
    if (b < 5000){
        int gid = b * 256 + threadIdx.x;     // 4 elems each
        float4 v = ((const float4*)node_feats)[gid];
        ushort4 o;
        o.x = f2b(v.x); o.y = f2b(v.y); o.z = f2b(v.z); o.w = f2b(v.w);
        ((ushort4*)nf)[gid] = o;
    } else if (b < 5256){
        int t = b - 5000;
        int c = t >> 6;                      // matrix 0..3
        int idx = (t & 63) * 256 + threadIdx.x;   // coalesced read
        const float* in   = (c == 0) ? proj_W : fc_W + (size_t)(c - 1) * 16384;
        unsigned short* o = (c == 0) ? projWT : fcWT + (size_t)(c - 1) * 16384;
        int k = idx >> 7, n = idx & 127;
        o[n * 128 + k] = f2b(in[idx]);       // scattered 2B write
    } else if (b < 5448){
        int idx = (b - 5256) * 256 + threadIdx.x;
        gruWb[idx] = f2b(gru_Wih[idx]);      // (384,128) already B^T layout
    } else {
        int e = (b - 5448) * 256 + threadIdx.x;
        atomicAdd(&deg8[(e & 7) * NNODES + dstp[e]], 1);   // 8-plane: 8x less line contention
    }
}

// ---------- single-dispatch decoupled-lookback scan over 8-plane degrees ----------
// 40 blocks x 256 threads, 1 int4 (4 nodes) per thread. Emits rowptr (padded prefix),
// degt (total degree), cur8 (per-plane cursors). state[b] = (aggregate<<32)|1, device scope.
__global__ __launch_bounds__(256) void scan_lookback(
        const int* __restrict__ deg8, int* __restrict__ rowptr, int* __restrict__ degt,
        int* __restrict__ cur8, unsigned long long* __restrict__ state){
    __shared__ int wincl[4];
    __shared__ int wexcl[4];
    __shared__ int blockT;
    __shared__ int baseSh;
    int b = blockIdx.x, t = threadIdx.x, lane = t & 63, wid = t >> 6;
    int i4 = b * 256 + t;
    bool ok = i4 < NNODES / 4;
    int4 d[8];
    #pragma unroll
    for (int x = 0; x < 8; x++)
        d[x] = ok ? ((const int4*)(deg8 + (size_t)x * NNODES))[i4] : make_int4(0, 0, 0, 0);
    int s0 = 0, s1 = 0, s2 = 0, s3 = 0;
    #pragma unroll
    for (int x = 0; x < 8; x++){ s0 += d[x].x; s1 += d[x].y; s2 += d[x].z; s3 += d[x].w; }
    int p0 = (s0 + 7) & ~7, p1 = (s1 + 7) & ~7;
    int p2 = (s2 + 7) & ~7, p3 = (s3 + 7) & ~7;
    int v = p0 + p1 + p2 + p3;
    int x = v;                                  // wave-inclusive scan
    #pragma unroll
    for (int dd = 1; dd < 64; dd <<= 1){
        int y = __shfl_up(x, dd, 64);
        if (lane >= dd) x += y;
    }
    if (lane == 63) wincl[wid] = x;
    __syncthreads();
    if (t == 0){
        int a = 0;
        #pragma unroll
        for (int i = 0; i < 4; i++){ wexcl[i] = a; a += wincl[i]; }
        blockT = a;
        __hip_atomic_store(&state[b], ((unsigned long long)(unsigned)a << 32) | 1ull,
                           __ATOMIC_RELEASE, __HIP_MEMORY_SCOPE_AGENT);
    }
    __syncthreads();
    // lookback: wave 0, lane i spins on predecessor i (< b); then 64-lane sum
    if (wid == 0){
        int contrib = 0;
        if (lane < b){
            unsigned long long st;
            do {
                st = __hip_atomic_load(&state[lane], __ATOMIC_ACQUIRE, __HIP_MEMORY_SCOPE_AGENT);
            } while (!(st & 1ull));
            contrib = (int)(st >> 32);
        }
        #pragma unroll
        for (int msk = 32; msk; msk >>= 1) contrib += __shfl_xor(contrib, msk, 64);
        if (lane == 0) baseSh = contrib;
    }
    __syncthreads();
    int base = baseSh;
    int excl = base + wexcl[wid] + (x - v);
    if (ok){
        int4 o = make_int4(excl, excl + p0, excl + p0 + p1, excl + p0 + p1 + p2);
        ((int4*)rowptr)[i4] = o;
        ((int4*)degt)[i4]   = make_int4(s0, s1, s2, s3);
        int o0 = o.x, o1 = o.y, o2 = o.z, o3 = o.w;
        #pragma unroll
        for (int xx = 0; xx < 8; xx++){
            ((int4*)(cur8 + (size_t)xx * NNODES))[i4] = make_int4(o0, o1, o2, o3);
            o0 += d[xx].x; o1 += d[xx].y; o2 += d[xx].z; o3 += d[xx].w;
        }
    }
    if (b == 39 && t == 0) rowptr[NNODES] = base + blockT;   // grand total
}

// ---------- merged dispatch: proj+fc0 gemm (blocks 0..624)  ||  CSR fill (blocks 625..3124)
// LDS 16KB (A tile / phase handoff only; B read direct from L2-resident global)
// so the LDS allocation doesn't throttle the latency-bound fill blocks' occupancy.
__global__ __launch_bounds__(256) void fill_proj(
        const int* __restrict__ src, const int* __restrict__ dst,
        int* __restrict__ cur8, int* __restrict__ esrc,
        const unsigned short* __restrict__ nf,
        const unsigned short* __restrict__ projWT, const float* __restrict__ proj_b,
        const unsigned short* __restrict__ fcWT0,
        unsigned short* __restrict__ h, unsigned short* __restrict__ feat,
        const float* __restrict__ al, const float* __restrict__ ar,
        float* __restrict__ elp, float* __restrict__ erp)
{
    __shared__ unsigned char ldsA[16384];
    int b = blockIdx.x;
    if (b >= 625){
        // ---- fill path (no LDS use) ----
        int e = (b - 625) * 256 + threadIdx.x;
        int d = dst[e];
        int pos = atomicAdd(&cur8[(e & 7) * NNODES + d], 1);
        esrc[pos] = src[e];
        return;
    }
    // ---- proj + fc0 path ----
    int w = threadIdx.x >> 6, lane = threadIdx.x & 63;
    int rsub = lane >> 4, c16 = lane & 15;
    long baseM = (long)b * 64;                   // 625 * 64 == 40000 exactly

    #pragma unroll
    for (int i = 0; i < 4; i++){
        int chunk = w * 4 + i;
        int r = chunk * 4 + rsub;
        int cg = c16 ^ (r & 15);
        g2l16((const unsigned char*)nf + (baseM + r) * 256 + cg * 16, ldsA + chunk * 1024);
    }
    __syncthreads();

    int no = w * 32;
    int q = lane >> 4, cl = lane & 15;
    f32x4 acc[4][2];
    #pragma unroll
    for (int i = 0; i < 4; i++)
        #pragma unroll
        for (int j = 0; j < 2; j++) acc[i][j] = (f32x4){0.f, 0.f, 0.f, 0.f};

    // phase A: h_tile = nf_tile @ projWT  (A from LDS, B direct from global/L2)
    #pragma unroll
    for (int kc = 0; kc < 4; kc++){
        int co = kc * 32 + q * 8;
        bf16x8 av[4], bv[2];
        #pragma unroll
        for (int mi = 0; mi < 4; mi++){
            int row = mi * 16 + cl;
            int cs = (kc * 4 + q) ^ (row & 15);
            av[mi] = *(const bf16x8*)(ldsA + row * 256 + cs * 16);
        }
        #pragma unroll
        for (int ni = 0; ni < 2; ni++)
            bv[ni] = *(const bf16x8*)(projWT + (no + ni * 16 + cl) * 128 + co);
        #pragma unroll
        for (int mi = 0; mi < 4; mi++)
            #pragma unroll
            for (int ni = 0; ni < 2; ni++)
                acc[mi][ni] = __builtin_amdgcn_mfma_f32_16x16x32_bf16(av[mi], bv[ni], acc[mi][ni], 0, 0, 0);
    }
    __syncthreads();   // all waves done reading ldsA; safe to overwrite

    // epilogue A: h (global bf16) + re-deposit bf16 into ldsA for phase B
    #pragma unroll
    for (int ni = 0; ni < 2; ni++){
        int j = no + ni * 16 + cl;
        float bvf = proj_b[j];
        #pragma unroll
        for (int mi = 0; mi < 4; mi++){
            #pragma unroll
            for (int reg = 0; reg < 4; reg++){
                int row = mi * 16 + q * 4 + reg;
                unsigned short bb = f2b(acc[mi][ni][reg] + bvf);
                h[(baseM + row) * 128 + j] = bb;
                *(unsigned short*)(ldsA + lds_off(row, j)) = bb;
            }
        }
    }
    __syncthreads();   // handoff writes visible

    #pragma unroll
    for (int i = 0; i < 4; i++)
        #pragma unroll
        for (int j = 0; j < 2; j++) acc[i][j] = (f32x4){0.f, 0.f, 0.f, 0.f};

    // phase B: feat_tile = h_tile @ fcWT0  (A from LDS, B direct from global/L2)
    #pragma unroll
    for (int kc = 0; kc < 4; kc++){
        int co = kc * 32 + q * 8;
        bf16x8 av[4], bv[2];
        #pragma unroll
        for (int mi = 0; mi < 4; mi++){
            int row = mi * 16 + cl;
            int cs = (kc * 4 + q) ^ (row & 15);
            av[mi] = *(const bf16x8*)(ldsA + row * 256 + cs * 16);
        }
        #pragma unroll
        for (int ni = 0; ni < 2; ni++)
            bv[ni] = *(const bf16x8*)(fcWT0 + (no + ni * 16 + cl) * 128 + co);
        #pragma unroll
        for (int mi = 0; mi < 4; mi++)
            #pragma unroll
            for (int ni = 0; ni < 2; ni++)
                acc[mi][ni] = __builtin_amdgcn_mfma_f32_16x16x32_bf16(av[mi], bv[ni], acc[mi][ni], 0, 0, 0);
    }

    // epilogue B: feat (bf16) + fused el/er for layer 0
    #pragma unroll
    for (int mi = 0; mi < 4; mi++){
        #pragma unroll
        for (int ni = 0; ni < 2; ni++){
            int gn = no + ni * 16 + cl;
            #pragma unroll
            for (int reg = 0; reg < 4; reg++){
                long gm = baseM + mi * 16 + q * 4 + reg;
                feat[gm * 128 + gn] = f2b(acc[mi][ni][reg]);
            }
        }
    }
    float al_lo = al[no + cl], al_hi = al[no + 16 + cl];
    float ar_lo = ar[no + cl], ar_hi = ar[no + 16 + cl];
    #pragma unroll
    for (int mi = 0; mi < 4; mi++){
        #pragma unroll
        for (int reg = 0; reg < 4; reg++){
            float pl = acc[mi][0][reg] * al_lo + acc[mi][1][reg] * al_hi;
            float pr = acc[mi][0][reg] * ar_lo + acc[mi][1][reg] * ar_hi;
            #pragma unroll
            for (int msk = 8; msk; msk >>= 1){
                pl += __shfl_xor(pl, msk, 64);
                pr += __shfl_xor(pr, msk, 64);
            }
            long gm = baseM + mi * 16 + q * 4 + reg;
            if (cl == 0){
                elp[gm * 4 + w] = pl;
                erp[gm * 4 + w] = pr;
            }
        }
    }
}

// ---------- GEMM: C[M x 128] = A[M x 128](bf16) * BT[128 x 128]^T (staged) ----------
// MT=64: 4 waves, each 64 rows x 32 cols. Fused el/er (wave w == head w).
template<int MT>
__global__ __launch_bounds__(256) void gemm_t(
        const unsigned short* __restrict__ A, const unsigned short* __restrict__ BT,
        const float* __restrict__ bias, void* __restrict__ C,
        int Mreal, int ldc, int outF32,
        const float* __restrict__ al, const float* __restrict__ ar,
        float* __restrict__ elp, float* __restrict__ erp)
{
    __shared__ unsigned char lds[MT * 256 + 32768];
    unsigned char* ldsA = lds;
    unsigned char* ldsB = lds + MT * 256;
    int w = threadIdx.x >> 6, lane = threadIdx.x & 63;
    int rsub = lane >> 4, c16 = lane & 15;
    long baseM = (long)blockIdx.x * MT;
    long baseN = (long)blockIdx.y * 128;

    #pragma unroll
    for (int i = 0; i < MT / 16; i++){
        int chunk = w * (MT / 16) + i;
        int r = chunk * 4 + rsub;
        int cg = c16 ^ (r & 15);
        long ar_ = baseM + r; if (ar_ >= Mreal) ar_ = Mreal - 1;
        g2l16((const unsigned char*)A + ar_ * 256 + cg * 16, ldsA + chunk * 1024);
    }
    #pragma unroll
    for (int i = 0; i < 8; i++){
        int chunk = w * 8 + i;
        int r = chunk * 4 + rsub;
        int cg = c16 ^ (r & 15);
        long br = baseN + r;
        g2l16((const unsigned char*)BT + br * 256 + cg * 16, ldsB + chunk * 1024);
    }
    __syncthreads();

    constexpr int MI = 4;
    constexpr int NI = (MT == 128) ? 4 : 2;
    int mo = (MT == 128) ? (w & 1) * 64 : 0;
    int no = (MT == 128) ? (w >> 1) * 64 : w * 32;
    int q = lane >> 4, cl = lane & 15;
    f32x4 acc[MI][NI];
    #pragma unroll
    for (int i = 0; i < MI; i++)
        #pragma unroll
        for (int j = 0; j < NI; j++) acc[i][j] = (f32x4){0.f, 0.f, 0.f, 0.f};

    #pragma unroll
    for (int kc = 0; kc < 4; kc++){
        bf16x8 av[MI], bv[NI];
        #pragma unroll
        for (int mi = 0; mi < MI; mi++){
            int row = mo + mi * 16 + cl;
            int cs = (kc * 4 + q) ^ (row & 15);
            av[mi] = *(const bf16x8*)(ldsA + row * 256 + cs * 16);
        }
        #pragma unroll
        for (int ni = 0; ni < NI; ni++){
            int row = no + ni * 16 + cl;
            int cs = (kc * 4 + q) ^ (row & 15);
            bv[ni] = *(const bf16x8*)(ldsB + row * 256 + cs * 16);
        }
        #pragma unroll
        for (int mi = 0; mi < MI; mi++)
            #pragma unroll
            for (int ni = 0; ni < NI; ni++)
                acc[mi][ni] = __builtin_amdgcn_mfma_f32_16x16x32_bf16(av[mi], bv[ni], acc[mi][ni], 0, 0, 0);
    }

    // epilogue: C/D layout col=lane&15, row=(lane>>4)*4+reg
    #pragma unroll
    for (int mi = 0; mi < MI; mi++){
        #pragma unroll
        for (int ni = 0; ni < NI; ni++){
            int gn = (int)baseN + no + ni * 16 + cl;
            float bvf = bias ? bias[gn] : 0.f;
            long gm0 = baseM + mo + mi * 16 + q * 4;
            #pragma unroll
            for (int reg = 0; reg < 4; reg++){
                float v = acc[mi][ni][reg] + bvf;
                long gm = gm0 + reg;
                if (gm < Mreal){
                    if (outF32) ((float*)C)[gm * ldc + gn] = v;
                    else ((unsigned short*)C)[gm * ldc + gn] = f2b(v);
                }
            }
        }
    }

    // fused el/er: wave w == head w (cols w*32..w*32+31). 16-lane xor reduction over cl.
    if (NI == 2 && al){
        float al_lo = al[no + cl], al_hi = al[no + 16 + cl];
        float ar_lo = ar[no + cl], ar_hi = ar[no + 16 + cl];
        #pragma unroll
        for (int mi = 0; mi < MI; mi++){
            #pragma unroll
            for (int reg = 0; reg < 4; reg++){
                float pl = acc[mi][0][reg] * al_lo + acc[mi][1][reg] * al_hi;
                float pr = acc[mi][0][reg] * ar_lo + acc[mi][1][reg] * ar_hi;
                #pragma unroll
                for (int msk = 8; msk; msk >>= 1){
                    pl += __shfl_xor(pl, msk, 64);
                    pr += __shfl_xor(pr, msk, 64);
                }
                long gm = baseM + mi * 16 + q * 4 + reg;
                if (cl == 0 && gm < Mreal){
                    elp[gm * 4 + w] = pl;
                    erp[gm * 4 + w] = pr;
                }
            }
        }
    }
}

// ---------- fused double GRU step, de-staged: B direct from L2-resident global; ----------
// only the step0->step1 handoff uses LDS (16KB). One barrier pair instead of twelve.
__global__ __launch_bounds__(256) void gru2x(
        const unsigned short* __restrict__ A, const unsigned short* __restrict__ BT,
        const float* __restrict__ bih, const float* __restrict__ bhh,
        float* __restrict__ out)
{
    __shared__ unsigned char ldsA[16384];
    int w = threadIdx.x >> 6, lane = threadIdx.x & 63;
    long baseM = (long)blockIdx.x * 64;          // 625 * 64 == 40000 exactly
    int no = w * 32;
    int q = lane >> 4, cl = lane & 15;

    #pragma unroll
    for (int s = 0; s < 2; s++){
        bf16x8 avall[4][4];               // [kc][mi]
        if (s == 0){
            #pragma unroll
            for (int kc = 0; kc < 4; kc++)
                #pragma unroll
                for (int mi = 0; mi < 4; mi++)
                    avall[kc][mi] = *(const bf16x8*)(A + (baseM + mi * 16 + cl) * 128 + kc * 32 + q * 8);
        } else {
            __syncthreads();              // s0 epilogue LDS writes visible
            #pragma unroll
            for (int kc = 0; kc < 4; kc++)
                #pragma unroll
                for (int mi = 0; mi < 4; mi++){
                    int row = mi * 16 + cl;
                    int cs = (kc * 4 + q) ^ (row & 15);
                    avall[kc][mi] = *(const bf16x8*)(ldsA + row * 256 + cs * 16);
                }
        }

        f32x4 acc[3][4][2];
        #pragma unroll
        for (int c = 0; c < 3; c++)
            #pragma unroll
            for (int i = 0; i < 4; i++)
                #pragma unroll
                for (int j = 0; j < 2; j++) acc[c][i][j] = (f32x4){0.f, 0.f, 0.f, 0.f};

        #pragma unroll
        for (int c = 0; c < 3; c++){
            #pragma unroll
            for (int kc = 0; kc < 4; kc++){
                bf16x8 bv[2];
                #pragma unroll
                for (int ni = 0; ni < 2; ni++)
                    bv[ni] = *(const bf16x8*)(BT + (c * 128 + no + ni * 16 + cl) * 128 + kc * 32 + q * 8);
                #pragma unroll
                for (int mi = 0; mi < 4; mi++)
                    #pragma unroll
                    for (int ni = 0; ni < 2; ni++)
                        acc[c][mi][ni] = __builtin_amdgcn_mfma_f32_16x16x32_bf16(avall[kc][mi], bv[ni], acc[c][mi][ni], 0, 0, 0);
            }
        }

        #pragma unroll
        for (int ni = 0; ni < 2; ni++){
            int j = no + ni * 16 + cl;
            float bir = bih[j]       + bhh[j];
            float biz = bih[128 + j] + bhh[128 + j];
            float bin = bih[256 + j];
            float bhn = bhh[256 + j];
            #pragma unroll
            for (int mi = 0; mi < 4; mi++){
                #pragma unroll
                for (int reg = 0; reg < 4; reg++){
                    int row = mi * 16 + q * 4 + reg;
                    float gr = acc[0][mi][ni][reg] + bir;
                    float gz = acc[1][mi][ni][reg] + biz;
                    float gn = acc[2][mi][ni][reg] + bin;
                    float r = fast_rcp(1.f + __expf(-gr));
                    float z = fast_rcp(1.f + __expf(-gz));
                    float ex = __expf(2.f * (gn + r * bhn));
                    float nn = (ex - 1.f) * fast_rcp(ex + 1.f);
                    float v = (1.f - z) * nn;
                    if (s == 0)
                        *(unsigned short*)(ldsA + lds_off(row, j)) = f2b(v);
                    else
                        out[(baseM + row) * 128 + j] = v;
                }
            }
        }
    }
}

// ---------- per-dst aggregation with fused edge weights ----------
__global__ __launch_bounds__(256) void aggregate(
        const int* __restrict__ rowptr, const int* __restrict__ degv,
        const int* __restrict__ esrc,
        const float* __restrict__ el, const float* __restrict__ er,
        const unsigned short* __restrict__ feat, const float* __restrict__ bias,
        unsigned short* __restrict__ h)
{
    int wid = threadIdx.x >> 6, lane = threadIdx.x & 63;
    int n = blockIdx.x * 4 + wid;
    int hh = lane >> 4;
    int d0 = lane * 2;
    unsigned doff = (unsigned)(d0 * 2);           // byte offset inside a feat row
    int beg = rowptr[n], end = rowptr[n + 1];
    int dg  = degv[n];
    float erw = er[(size_t)n * 4 + hh];
    float s = 0.f, a0 = 0.f, a1 = 0.f;
    const char* fbc = (const char*)feat;
    const int*  ep  = esrc + beg;

    if (beg < end){
        int4 sA = *(const int4*)(ep);
        int4 sB = *(const int4*)(ep + 4);
        float e0=0.f,e1=0.f,e2=0.f,e3=0.f,e4=0.f,e5=0.f,e6=0.f,e7=0.f;
        unsigned f0=0,f1=0,f2=0,f3=0,f4=0,f5=0,f6=0,f7=0;
        int rprev = 0;                // dummy group: all weights 0
        int rcur  = dg;
        for (int p = beg; p < end; p += 8){
            float g0 = el[(((unsigned)sA.x) << 2) + hh];
            float g1 = el[(((unsigned)sA.y) << 2) + hh];
            float g2 = el[(((unsigned)sA.z) << 2) + hh];
            float g3 = el[(((unsigned)sA.w) << 2) + hh];
            float g4 = el[(((unsigned)sB.x) << 2) + hh];
            float g5 = el[(((unsigned)sB.y) << 2) + hh];
            float g6 = el[(((unsigned)sB.z) << 2) + hh];
            float g7 = el[(((unsigned)sB.w) << 2) + hh];
            unsigned c0 = *(const unsigned*)(fbc + ((((unsigned)sA.x) << 8) + doff));
            unsigned c1 = *(const unsigned*)(fbc + ((((unsigned)sA.y) << 8) + doff));
            unsigned c2 = *(const unsigned*)(fbc + ((((unsigned)sA.z) << 8) + doff));
            unsigned c3 = *(const unsigned*)(fbc + ((((unsigned)sA.w) << 8) + doff));
            unsigned c4 = *(const unsigned*)(fbc + ((((unsigned)sB.x) << 8) + doff));
            unsigned c5 = *(const unsigned*)(fbc + ((((unsigned)sB.y) << 8) + doff));
            unsigned c6 = *(const unsigned*)(fbc + ((((unsigned)sB.z) << 8) + doff));
            unsigned c7 = *(const unsigned*)(fbc + ((((unsigned)sB.w) << 8) + doff));
            int4 nA = *(const int4*)(ep + 8);
            int4 nB = *(const int4*)(ep + 12);
            float w0 = wcalc(e0, erw, 0, rprev);
            float w1 = wcalc(e1, erw, 1, rprev);
            float w2 = wcalc(e2, erw, 2, rprev);
            float w3 = wcalc(e3, erw, 3, rprev);
            float w4 = wcalc(e4, erw, 4, rprev);
            float w5 = wcalc(e5, erw, 5, rprev);
            float w6 = wcalc(e6, erw, 6, rprev);
            float w7 = wcalc(e7, erw, 7, rprev);
            s += ((w0 + w1) + (w2 + w3)) + ((w4 + w5) + (w6 + w7));
            a0 = fmaf(w0, bl(f0), fmaf(w1, bl(f1), fmaf(w2, bl(f2), fmaf(w3, bl(f3), a0))));
            a0 = fmaf(w4, bl(f4), fmaf(w5, bl(f5), fmaf(w6, bl(f6), fmaf(w7, bl(f7), a0))));
            a1 = fmaf(w0, bh(f0), fmaf(w1, bh(f1), fmaf(w2, bh(f2), fmaf(w3, bh(f3), a1))));
            a1 = fmaf(w4, bh(f4), fmaf(w5, bh(f5), fmaf(w6, bh(f6), fmaf(w7, bh(f7), a1))));
            e0 = g0; e1 = g1; e2 = g2; e3 = g3; e4 = g4; e5 = g5; e6 = g6; e7 = g7;
            f0 = c0; f1 = c1; f2 = c2; f3 = c3; f4 = c4; f5 = c5; f6 = c6; f7 = c7;
            sA = nA; sB = nB;
            rprev = rcur; rcur -= 8;
            ep += 8;
        }
        float w0 = wcalc(e0, erw, 0, rprev);
        float w1 = wcalc(e1, erw, 1, rprev);
        float w2 = wcalc(e2, erw, 2, rprev);
        float w3 = wcalc(e3, erw, 3, rprev);
        float w4 = wcalc(e4, erw, 4, rprev);
        float w5 = wcalc(e5, erw, 5, rprev);
        float w6 = wcalc(e6, erw, 6, rprev);
        float w7 = wcalc(e7, erw, 7, rprev);
        s += ((w0 + w1) + (w2 + w3)) + ((w4 + w5) + (w6 + w7));
        a0 = fmaf(w0, bl(f0), fmaf(w1, bl(f1), fmaf(w2, bl(f2), fmaf(w3, bl(f3), a0))));
        a0 = fmaf(w4, bl(f4), fmaf(w5, bl(f5), fmaf(w6, bl(f6), fmaf(w7, bl(f7), a0))));
        a1 = fmaf(w0, bh(f0), fmaf(w1, bh(f1), fmaf(w2, bh(f2), fmaf(w3, bh(f3), a1))));
        a1 = fmaf(w4, bh(f4), fmaf(w5, bh(f5), fmaf(w6, bh(f6), fmaf(w7, bh(f7), a1))));
    }
    float inv = (s > 0.f) ? fast_rcp(s) : 0.f;
    unsigned hv = *(const unsigned*)(h + (size_t)n * 128 + d0);
    float x0 = a0 * inv + bl(hv) + bias[d0];
    float x1 = a1 * inv + bh(hv) + bias[d0 + 1];
    x0 = (x0 > 0.f) ? x0 : expm1f(x0);              // elu
    x1 = (x1 > 0.f) ? x1 : expm1f(x1);
    unsigned outv = (unsigned)f2b(x0) | ((unsigned)f2b(x1) << 16);
    *(unsigned*)(h + (size_t)n * 128 + d0) = outv;
}

extern "C" void kernel_launch(void* const* d_in, const int* in_sizes, int n_in,
                              void* d_out, int out_size, void* d_ws, size_t ws_size,
                              hipStream_t stream) {
    const float* node_feats = (const float*)d_in[0];
    const int*   srcp       = (const int*)d_in[1];
    const int*   dstp       = (const int*)d_in[2];
    const float* proj_W     = (const float*)d_in[3];
    const float* proj_b     = (const float*)d_in[4];
    const float* fc_W       = (const float*)d_in[5];
    const float* attn_l     = (const float*)d_in[6];
    const float* attn_r     = (const float*)d_in[7];
    const float* conv_bias  = (const float*)d_in[8];
    const float* gru_Wih    = (const float*)d_in[9];
    // d_in[10] gru_Whh unused (h0 == 0)
    const float* gru_bih    = (const float*)d_in[11];
    const float* gru_bhh    = (const float*)d_in[12];
    float* outp = (float*)d_out;

    char* ws = (char*)d_ws;
    size_t off = 0;
    auto carve = [&](size_t bytes) -> char* {
        char* p = ws + off;
        off += (bytes + 255) & ~(size_t)255;
        return p;
    };
    // deg8, scan state, esrc carved adjacently -> single memset covers all three
    int*                deg8   = (int*)carve((size_t)8 * NNODES * 4);   // 1,280,000 B (mult of 256)
    unsigned long long* state  = (unsigned long long*)carve(512);       // 40 x 8B lookback state
    int*                esrc   = (int*)carve((size_t)(PADCAP + 32) * 4);
    int*                rowptr = (int*)carve((size_t)(NNODES + 1) * 4);
    int*                degt   = (int*)carve((size_t)NNODES * 4);
    int*                cur8   = (int*)carve((size_t)8 * NNODES * 4);
    float*              el     = (float*)carve((size_t)NNODES * 4 * 4);
    float*              er     = (float*)carve((size_t)NNODES * 4 * 4);
    unsigned short*     projWT = (unsigned short*)carve(16384 * 2);
    unsigned short*     fcWT   = (unsigned short*)carve(3 * 16384 * 2);
    unsigned short*     gruWb  = (unsigned short*)carve(49152 * 2);
    unsigned short*     nf     = (unsigned short*)carve((size_t)NNODES * 128 * 2);
    unsigned short*     h      = (unsigned short*)carve((size_t)M2PAD * 128 * 2);
    unsigned short*     feat   = (unsigned short*)carve((size_t)M2PAD * 128 * 2);
    (void)ws_size; (void)in_sizes; (void)n_in; (void)out_size;

    // single memset: deg8 + lookback state + esrc (pad slots gather node 0; weight 0 via deg)
    hipMemsetAsync(deg8, 0,
                   (size_t)8 * NNODES * 4 + 512 + (((size_t)(PADCAP + 32) * 4 + 255) & ~(size_t)255),
                   stream);
    prep_all<<<7948, 256, 0, stream>>>(node_feats, proj_W, fc_W, gru_Wih, dstp,
                                       nf, projWT, fcWT, gruWb, deg8);
    scan_lookback<<<40, 256, 0, stream>>>(deg8, rowptr, degt, cur8, state);

    // merged: CSR fill (atomic/scatter, latency-bound)  ||  proj + layer-0 fc gemm (MFMA)
    fill_proj<<<625 + NEDGES / 256, 256, 0, stream>>>(srcp, dstp, cur8, esrc,
                                                      nf, projWT, proj_b, fcWT, h, feat,
                                                      attn_l, attn_r, el, er);

    // 3 GAT layers (layer 0's gemm already fused above)
    for (int l = 0; l < 3; l++){
        if (l > 0){
            gemm_t<64><<<dim3(625, 1), 256, 0, stream>>>(h, fcWT + l * 16384, nullptr, feat, NNODES, 128, 0,
                                                         attn_l + l * 128, attn_r + l * 128, el, er);
        }
        aggregate<<<NNODES / 4, 256, 0, stream>>>(rowptr, degt, esrc, el, er, feat,
                                                  conv_bias + l * 128, h);
    }

    // fused double GRU step (de-staged: 16KB LDS, single barrier)
    gru2x<<<625, 256, 0, stream>>>(h, gruWb, gru_bih, gru_bhh, outp);
}

// Round 13
// 360.895 us; speedup vs baseline: 1.0002x; 1.0002x over previous
//
#include <hip/hip_runtime.h>
#include <hip/hip_bf16.h>

#define NNODES 40000
#define NEDGES 640000
#define M2PAD  40064
#define HID    128
#define PADCAP 920064                 // >= NEDGES + 7*NNODES, multiple of 256

typedef __attribute__((ext_vector_type(8))) short bf16x8;
typedef __attribute__((ext_vector_type(4))) float f32x4;

__device__ __forceinline__ float bl(unsigned u){ return __uint_as_float(u << 16); }
__device__ __forceinline__ float bh(unsigned u){ return __uint_as_float(u & 0xFFFF0000u); }
__device__ __forceinline__ unsigned short f2b(float f){
    unsigned u = __float_as_uint(f);
    u = (u + 0x7FFFu + ((u >> 16) & 1u)) >> 16;   // round-to-nearest-even
    return (unsigned short)u;
}
__device__ __forceinline__ float fast_rcp(float x){ return __builtin_amdgcn_rcpf(x); }

// edge weight: lrelu(el+er) -> exp, zero for pad slots (j >= remaining real edges)
__device__ __forceinline__ float wcalc(float e, float erw, int j, int rem){
    float t = e + erw;
    t = (t > 0.f) ? t : 0.2f * t;
    t = __expf(t);
    return (j < rem) ? t : 0.f;
}

// LDS byte offset for bf16 element (row, col) in the XOR-swizzled layout the
// MFMA fragment reader uses: chunk (col>>3) xor'd with (row&15), 2B within chunk.
__device__ __forceinline__ unsigned lds_off(int row, int col){
    return (unsigned)(row * 256 + (((col >> 3) ^ (row & 15)) << 4) + ((col & 7) << 1));
}

// ---------- prep: weight transpose (0..255) + gru cvt (256..447)
//            + degree count into 8 planes (448..2947) ----------
// (node_feats f32->bf16 conversion now fused into fill_proj phase A)
__global__ void prep_all(const float* __restrict__ proj_W, const float* __restrict__ fc_W,
                         const float* __restrict__ gru_Wih, const int* __restrict__ dstp,
                         unsigned short* __restrict__ projWT, unsigned short* __restrict__ fcWT,
                         unsigned short* __restrict__ gruWb, int* __restrict__ deg8){
    int b = blockIdx.x;
    if (b < 256){
        int c = b >> 6;                      // matrix 0..3
        int idx = (b & 63) * 256 + threadIdx.x;   // coalesced read
        const float* in   = (c == 0) ? proj_W : fc_W + (size_t)(c - 1) * 16384;
        unsigned short* o = (c == 0) ? projWT : fcWT + (size_t)(c - 1) * 16384;
        int k = idx >> 7, n = idx & 127;
        o[n * 128 + k] = f2b(in[idx]);       // scattered 2B write
    } else if (b < 448){
        int idx = (b - 256) * 256 + threadIdx.x;
        gruWb[idx] = f2b(gru_Wih[idx]);      // (384,128) already B^T layout
    } else {
        int e = (b - 448) * 256 + threadIdx.x;
        atomicAdd(&deg8[(e & 7) * NNODES + dstp[e]], 1);   // 8-plane: 8x less line contention
    }
}

// ---------- single-dispatch decoupled-lookback scan over 8-plane degrees ----------
// 40 blocks x 256 threads, 1 int4 (4 nodes) per thread. Emits rowptr (padded prefix),
// degt (total degree), cur8 (per-plane cursors). state[b] = (aggregate<<32)|1, device scope.
__global__ __launch_bounds__(256) void scan_lookback(
        const int* __restrict__ deg8, int* __restrict__ rowptr, int* __restrict__ degt,
        int* __restrict__ cur8, unsigned long long* __restrict__ state){
    __shared__ int wincl[4];
    __shared__ int wexcl[4];
    __shared__ int blockT;
    __shared__ int baseSh;
    int b = blockIdx.x, t = threadIdx.x, lane = t & 63, wid = t >> 6;
    int i4 = b * 256 + t;
    bool ok = i4 < NNODES / 4;
    int4 d[8];
    #pragma unroll
    for (int x = 0; x < 8; x++)
        d[x] = ok ? ((const int4*)(deg8 + (size_t)x * NNODES))[i4] : make_int4(0, 0, 0, 0);
    int s0 = 0, s1 = 0, s2 = 0, s3 = 0;
    #pragma unroll
    for (int x = 0; x < 8; x++){ s0 += d[x].x; s1 += d[x].y; s2 += d[x].z; s3 += d[x].w; }
    int p0 = (s0 + 7) & ~7, p1 = (s1 + 7) & ~7;
    int p2 = (s2 + 7) & ~7, p3 = (s3 + 7) & ~7;
    int v = p0 + p1 + p2 + p3;
    int x = v;                                  // wave-inclusive scan
    #pragma unroll
    for (int dd = 1; dd < 64; dd <<= 1){
        int y = __shfl_up(x, dd, 64);
        if (lane >= dd) x += y;
    }
    if (lane == 63) wincl[wid] = x;
    __syncthreads();
    if (t == 0){
        int a = 0;
        #pragma unroll
        for (int i = 0; i < 4; i++){ wexcl[i] = a; a += wincl[i]; }
        blockT = a;
        __hip_atomic_store(&state[b], ((unsigned long long)(unsigned)a << 32) | 1ull,
                           __ATOMIC_RELEASE, __HIP_MEMORY_SCOPE_AGENT);
    }
    __syncthreads();
    // lookback: wave 0, lane i spins on predecessor i (< b); then 64-lane sum
    if (wid == 0){
        int contrib = 0;
        if (lane < b){
            unsigned long long st;
            do {
                st = __hip_atomic_load(&state[lane], __ATOMIC_ACQUIRE, __HIP_MEMORY_SCOPE_AGENT);
            } while (!(st & 1ull));
            contrib = (int)(st >> 32);
        }
        #pragma unroll
        for (int msk = 32; msk; msk >>= 1) contrib += __shfl_xor(contrib, msk, 64);
        if (lane == 0) baseSh = contrib;
    }
    __syncthreads();
    int base = baseSh;
    int excl = base + wexcl[wid] + (x - v);
    if (ok){
        int4 o = make_int4(excl, excl + p0, excl + p0 + p1, excl + p0 + p1 + p2);
        ((int4*)rowptr)[i4] = o;
        ((int4*)degt)[i4]   = make_int4(s0, s1, s2, s3);
        int o0 = o.x, o1 = o.y, o2 = o.z, o3 = o.w;
        #pragma unroll
        for (int xx = 0; xx < 8; xx++){
            ((int4*)(cur8 + (size_t)xx * NNODES))[i4] = make_int4(o0, o1, o2, o3);
            o0 += d[xx].x; o1 += d[xx].y; o2 += d[xx].z; o3 += d[xx].w;
        }
    }
    if (b == 39 && t == 0) rowptr[NNODES] = base + blockT;   // grand total
}

// ---------- merged dispatch: proj+fc0 gemm (blocks 0..624)  ||  CSR fill (blocks 625..3124)
// Phase A reads node_feats f32 DIRECT (cvt in-register); LDS (16KB) only for the
// phase A -> phase B handoff. B operands direct from L2-resident global.
__global__ __launch_bounds__(256) void fill_proj(
        const int* __restrict__ src, const int* __restrict__ dst,
        int* __restrict__ cur8, int* __restrict__ esrc,
        const float* __restrict__ node_feats,
        const unsigned short* __restrict__ projWT, const float* __restrict__ proj_b,
        const unsigned short* __restrict__ fcWT0,
        unsigned short* __restrict__ h, unsigned short* __restrict__ feat,
        const float* __restrict__ al, const float* __restrict__ ar,
        float* __restrict__ elp, float* __restrict__ erp)
{
    __shared__ unsigned char ldsA[16384];
    int b = blockIdx.x;
    if (b >= 625){
        // ---- fill path (no LDS use) ----
        int e = (b - 625) * 256 + threadIdx.x;
        int d = dst[e];
        int pos = atomicAdd(&cur8[(e & 7) * NNODES + d], 1);
        esrc[pos] = src[e];
        return;
    }
    // ---- proj + fc0 path ----
    int w = threadIdx.x >> 6, lane = threadIdx.x & 63;
    long baseM = (long)b * 64;                   // 625 * 64 == 40000 exactly
    int no = w * 32;
    int q = lane >> 4, cl = lane & 15;

    f32x4 acc[4][2];
    #pragma unroll
    for (int i = 0; i < 4; i++)
        #pragma unroll
        for (int j = 0; j < 2; j++) acc[i][j] = (f32x4){0.f, 0.f, 0.f, 0.f};

    // phase A: h_tile = nf_tile @ projWT  (A from f32 global w/ in-register cvt; B direct)
    #pragma unroll
    for (int kc = 0; kc < 4; kc++){
        int co = kc * 32 + q * 8;
        bf16x8 av[4], bv[2];
        #pragma unroll
        for (int mi = 0; mi < 4; mi++){
            const float* ap = node_feats + (baseM + mi * 16 + cl) * 128 + co;
            float4 x0 = *(const float4*)(ap);
            float4 x1 = *(const float4*)(ap + 4);
            bf16x8 t;
            t[0] = (short)f2b(x0.x); t[1] = (short)f2b(x0.y);
            t[2] = (short)f2b(x0.z); t[3] = (short)f2b(x0.w);
            t[4] = (short)f2b(x1.x); t[5] = (short)f2b(x1.y);
            t[6] = (short)f2b(x1.z); t[7] = (short)f2b(x1.w);
            av[mi] = t;
        }
        #pragma unroll
        for (int ni = 0; ni < 2; ni++)
            bv[ni] = *(const bf16x8*)(projWT + (no + ni * 16 + cl) * 128 + co);
        #pragma unroll
        for (int mi = 0; mi < 4; mi++)
            #pragma unroll
            for (int ni = 0; ni < 2; ni++)
                acc[mi][ni] = __builtin_amdgcn_mfma_f32_16x16x32_bf16(av[mi], bv[ni], acc[mi][ni], 0, 0, 0);
    }

    // epilogue A: h (global bf16) + deposit bf16 into ldsA (swizzled) for phase B
    #pragma unroll
    for (int ni = 0; ni < 2; ni++){
        int j = no + ni * 16 + cl;
        float bvf = proj_b[j];
        #pragma unroll
        for (int mi = 0; mi < 4; mi++){
            #pragma unroll
            for (int reg = 0; reg < 4; reg++){
                int row = mi * 16 + q * 4 + reg;
                unsigned short bb = f2b(acc[mi][ni][reg] + bvf);
                h[(baseM + row) * 128 + j] = bb;
                *(unsigned short*)(ldsA + lds_off(row, j)) = bb;
            }
        }
    }
    __syncthreads();   // handoff writes visible

    #pragma unroll
    for (int i = 0; i < 4; i++)
        #pragma unroll
        for (int j = 0; j < 2; j++) acc[i][j] = (f32x4){0.f, 0.f, 0.f, 0.f};

    // phase B: feat_tile = h_tile @ fcWT0  (A from LDS, B direct from global/L2)
    #pragma unroll
    for (int kc = 0; kc < 4; kc++){
        int co = kc * 32 + q * 8;
        bf16x8 av[4], bv[2];
        #pragma unroll
        for (int mi = 0; mi < 4; mi++){
            int row = mi * 16 + cl;
            int cs = (kc * 4 + q) ^ (row & 15);
            av[mi] = *(const bf16x8*)(ldsA + row * 256 + cs * 16);
        }
        #pragma unroll
        for (int ni = 0; ni < 2; ni++)
            bv[ni] = *(const bf16x8*)(fcWT0 + (no + ni * 16 + cl) * 128 + co);
        #pragma unroll
        for (int mi = 0; mi < 4; mi++)
            #pragma unroll
            for (int ni = 0; ni < 2; ni++)
                acc[mi][ni] = __builtin_amdgcn_mfma_f32_16x16x32_bf16(av[mi], bv[ni], acc[mi][ni], 0, 0, 0);
    }

    // epilogue B: feat (bf16) + fused el/er for layer 0
    #pragma unroll
    for (int mi = 0; mi < 4; mi++){
        #pragma unroll
        for (int ni = 0; ni < 2; ni++){
            int gn = no + ni * 16 + cl;
            #pragma unroll
            for (int reg = 0; reg < 4; reg++){
                long gm = baseM + mi * 16 + q * 4 + reg;
                feat[gm * 128 + gn] = f2b(acc[mi][ni][reg]);
            }
        }
    }
    float al_lo = al[no + cl], al_hi = al[no + 16 + cl];
    float ar_lo = ar[no + cl], ar_hi = ar[no + 16 + cl];
    #pragma unroll
    for (int mi = 0; mi < 4; mi++){
        #pragma unroll
        for (int reg = 0; reg < 4; reg++){
            float pl = acc[mi][0][reg] * al_lo + acc[mi][1][reg] * al_hi;
            float pr = acc[mi][0][reg] * ar_lo + acc[mi][1][reg] * ar_hi;
            #pragma unroll
            for (int msk = 8; msk; msk >>= 1){
                pl += __shfl_xor(pl, msk, 64);
                pr += __shfl_xor(pr, msk, 64);
            }
            long gm = baseM + mi * 16 + q * 4 + reg;
            if (cl == 0){
                elp[gm * 4 + w] = pl;
                erp[gm * 4 + w] = pr;
            }
        }
    }
}

// ---------- GEMM, fully de-staged (0 LDS): A/B fragments direct from global/L2 ----------
// 625 blocks x 64 rows; wave w covers cols w*32..w*32+31. Fused el/er.
__global__ __launch_bounds__(256) void gemm_t(
        const unsigned short* __restrict__ A, const unsigned short* __restrict__ BT,
        unsigned short* __restrict__ C,
        const float* __restrict__ al, const float* __restrict__ ar,
        float* __restrict__ elp, float* __restrict__ erp)
{
    int w = threadIdx.x >> 6, lane = threadIdx.x & 63;
    long baseM = (long)blockIdx.x * 64;
    int no = w * 32;
    int q = lane >> 4, cl = lane & 15;

    f32x4 acc[4][2];
    #pragma unroll
    for (int i = 0; i < 4; i++)
        #pragma unroll
        for (int j = 0; j < 2; j++) acc[i][j] = (f32x4){0.f, 0.f, 0.f, 0.f};

    #pragma unroll
    for (int kc = 0; kc < 4; kc++){
        int co = kc * 32 + q * 8;
        bf16x8 av[4], bv[2];
        #pragma unroll
        for (int mi = 0; mi < 4; mi++)
            av[mi] = *(const bf16x8*)(A + (baseM + mi * 16 + cl) * 128 + co);
        #pragma unroll
        for (int ni = 0; ni < 2; ni++)
            bv[ni] = *(const bf16x8*)(BT + (no + ni * 16 + cl) * 128 + co);
        #pragma unroll
        for (int mi = 0; mi < 4; mi++)
            #pragma unroll
            for (int ni = 0; ni < 2; ni++)
                acc[mi][ni] = __builtin_amdgcn_mfma_f32_16x16x32_bf16(av[mi], bv[ni], acc[mi][ni], 0, 0, 0);
    }

    // epilogue: C/D layout col=lane&15, row=(lane>>4)*4+reg   (625*64 == 40000 exactly)
    #pragma unroll
    for (int mi = 0; mi < 4; mi++){
        #pragma unroll
        for (int ni = 0; ni < 2; ni++){
            int gn = no + ni * 16 + cl;
            long gm0 = baseM + mi * 16 + q * 4;
            #pragma unroll
            for (int reg = 0; reg < 4; reg++)
                C[(gm0 + reg) * 128 + gn] = f2b(acc[mi][ni][reg]);
        }
    }

    // fused el/er: wave w == head w. 16-lane xor reduction over cl.
    float al_lo = al[no + cl], al_hi = al[no + 16 + cl];
    float ar_lo = ar[no + cl], ar_hi = ar[no + 16 + cl];
    #pragma unroll
    for (int mi = 0; mi < 4; mi++){
        #pragma unroll
        for (int reg = 0; reg < 4; reg++){
            float pl = acc[mi][0][reg] * al_lo + acc[mi][1][reg] * al_hi;
            float pr = acc[mi][0][reg] * ar_lo + acc[mi][1][reg] * ar_hi;
            #pragma unroll
            for (int msk = 8; msk; msk >>= 1){
                pl += __shfl_xor(pl, msk, 64);
                pr += __shfl_xor(pr, msk, 64);
            }
            long gm = baseM + mi * 16 + q * 4 + reg;
            if (cl == 0){
                elp[gm * 4 + w] = pl;
                erp[gm * 4 + w] = pr;
            }
        }
    }
}

// ---------- fused double GRU step, de-staged: B direct from L2-resident global; ----------
// only the step0->step1 handoff uses LDS (16KB). One barrier instead of twelve.
__global__ __launch_bounds__(256) void gru2x(
        const unsigned short* __restrict__ A, const unsigned short* __restrict__ BT,
        const float* __restrict__ bih, const float* __restrict__ bhh,
        float* __restrict__ out)
{
    __shared__ unsigned char ldsA[16384];
    int w = threadIdx.x >> 6, lane = threadIdx.x & 63;
    long baseM = (long)blockIdx.x * 64;          // 625 * 64 == 40000 exactly
    int no = w * 32;
    int q = lane >> 4, cl = lane & 15;

    #pragma unroll
    for (int s = 0; s < 2; s++){
        bf16x8 avall[4][4];               // [kc][mi]
        if (s == 0){
            #pragma unroll
            for (int kc = 0; kc < 4; kc++)
                #pragma unroll
                for (int mi = 0; mi < 4; mi++)
                    avall[kc][mi] = *(const bf16x8*)(A + (baseM + mi * 16 + cl) * 128 + kc * 32 + q * 8);
        } else {
            __syncthreads();              // s0 epilogue LDS writes visible
            #pragma unroll
            for (int kc = 0; kc < 4; kc++)
                #pragma unroll
                for (int mi = 0; mi < 4; mi++){
                    int row = mi * 16 + cl;
                    int cs = (kc * 4 + q) ^ (row & 15);
                    avall[kc][mi] = *(const bf16x8*)(ldsA + row * 256 + cs * 16);
                }
        }

        f32x4 acc[3][4][2];
        #pragma unroll
        for (int c = 0; c < 3; c++)
            #pragma unroll
            for (int i = 0; i < 4; i++)
                #pragma unroll
                for (int j = 0; j < 2; j++) acc[c][i][j] = (f32x4){0.f, 0.f, 0.f, 0.f};

        #pragma unroll
        for (int c = 0; c < 3; c++){
            #pragma unroll
            for (int kc = 0; kc < 4; kc++){
                bf16x8 bv[2];
                #pragma unroll
                for (int ni = 0; ni < 2; ni++)
                    bv[ni] = *(const bf16x8*)(BT + (c * 128 + no + ni * 16 + cl) * 128 + kc * 32 + q * 8);
                #pragma unroll
                for (int mi = 0; mi < 4; mi++)
                    #pragma unroll
                    for (int ni = 0; ni < 2; ni++)
                        acc[c][mi][ni] = __builtin_amdgcn_mfma_f32_16x16x32_bf16(avall[kc][mi], bv[ni], acc[c][mi][ni], 0, 0, 0);
            }
        }

        #pragma unroll
        for (int ni = 0; ni < 2; ni++){
            int j = no + ni * 16 + cl;
            float bir = bih[j]       + bhh[j];
            float biz = bih[128 + j] + bhh[128 + j];
            float bin = bih[256 + j];
            float bhn = bhh[256 + j];
            #pragma unroll
            for (int mi = 0; mi < 4; mi++){
                #pragma unroll
                for (int reg = 0; reg < 4; reg++){
                    int row = mi * 16 + q * 4 + reg;
                    float gr = acc[0][mi][ni][reg] + bir;
                    float gz = acc[1][mi][ni][reg] + biz;
                    float gn = acc[2][mi][ni][reg] + bin;
                    float r = fast_rcp(1.f + __expf(-gr));
                    float z = fast_rcp(1.f + __expf(-gz));
                    float ex = __expf(2.f * (gn + r * bhn));
                    float nn = (ex - 1.f) * fast_rcp(ex + 1.f);
                    float v = (1.f - z) * nn;
                    if (s == 0)
                        *(unsigned short*)(ldsA + lds_off(row, j)) = f2b(v);
                    else
                        out[(baseM + row) * 128 + j] = v;
                }
            }
        }
    }
}

// ---------- per-dst aggregation with fused edge weights ----------
__global__ __launch_bounds__(256) void aggregate(
        const int* __restrict__ rowptr, const int* __restrict__ degv,
        const int* __restrict__ esrc,
        const float* __restrict__ el, const float* __restrict__ er,
        const unsigned short* __restrict__ feat, const float* __restrict__ bias,
        unsigned short* __restrict__ h)
{
    int wid = threadIdx.x >> 6, lane = threadIdx.x & 63;
    int n = blockIdx.x * 4 + wid;
    int hh = lane >> 4;
    int d0 = lane * 2;
    unsigned doff = (unsigned)(d0 * 2);           // byte offset inside a feat row
    int beg = rowptr[n], end = rowptr[n + 1];
    int dg  = degv[n];
    float erw = er[(size_t)n * 4 + hh];
    float s = 0.f, a0 = 0.f, a1 = 0.f;
    const char* fbc = (const char*)feat;
    const int*  ep  = esrc + beg;

    if (beg < end){
        int4 sA = *(const int4*)(ep);
        int4 sB = *(const int4*)(ep + 4);
        float e0=0.f,e1=0.f,e2=0.f,e3=0.f,e4=0.f,e5=0.f,e6=0.f,e7=0.f;
        unsigned f0=0,f1=0,f2=0,f3=0,f4=0,f5=0,f6=0,f7=0;
        int rprev = 0;                // dummy group: all weights 0
        int rcur  = dg;
        for (int p = beg; p < end; p += 8){
            float g0 = el[(((unsigned)sA.x) << 2) + hh];
            float g1 = el[(((unsigned)sA.y) << 2) + hh];
            float g2 = el[(((unsigned)sA.z) << 2) + hh];
            float g3 = el[(((unsigned)sA.w) << 2) + hh];
            float g4 = el[(((unsigned)sB.x) << 2) + hh];
            float g5 = el[(((unsigned)sB.y) << 2) + hh];
            float g6 = el[(((unsigned)sB.z) << 2) + hh];
            float g7 = el[(((unsigned)sB.w) << 2) + hh];
            unsigned c0 = *(const unsigned*)(fbc + ((((unsigned)sA.x) << 8) + doff));
            unsigned c1 = *(const unsigned*)(fbc + ((((unsigned)sA.y) << 8) + doff));
            unsigned c2 = *(const unsigned*)(fbc + ((((unsigned)sA.z) << 8) + doff));
            unsigned c3 = *(const unsigned*)(fbc + ((((unsigned)sA.w) << 8) + doff));
            unsigned c4 = *(const unsigned*)(fbc + ((((unsigned)sB.x) << 8) + doff));
            unsigned c5 = *(const unsigned*)(fbc + ((((unsigned)sB.y) << 8) + doff));
            unsigned c6 = *(const unsigned*)(fbc + ((((unsigned)sB.z) << 8) + doff));
            unsigned c7 = *(const unsigned*)(fbc + ((((unsigned)sB.w) << 8) + doff));
            int4 nA = *(const int4*)(ep + 8);
            int4 nB = *(const int4*)(ep + 12);
            float w0 = wcalc(e0, erw, 0, rprev);
            float w1 = wcalc(e1, erw, 1, rprev);
            float w2 = wcalc(e2, erw, 2, rprev);
            float w3 = wcalc(e3, erw, 3, rprev);
            float w4 = wcalc(e4, erw, 4, rprev);
            float w5 = wcalc(e5, erw, 5, rprev);
            float w6 = wcalc(e6, erw, 6, rprev);
            float w7 = wcalc(e7, erw, 7, rprev);
            s += ((w0 + w1) + (w2 + w3)) + ((w4 + w5) + (w6 + w7));
            a0 = fmaf(w0, bl(f0), fmaf(w1, bl(f1), fmaf(w2, bl(f2), fmaf(w3, bl(f3), a0))));
            a0 = fmaf(w4, bl(f4), fmaf(w5, bl(f5), fmaf(w6, bl(f6), fmaf(w7, bl(f7), a0))));
            a1 = fmaf(w0, bh(f0), fmaf(w1, bh(f1), fmaf(w2, bh(f2), fmaf(w3, bh(f3), a1))));
            a1 = fmaf(w4, bh(f4), fmaf(w5, bh(f5), fmaf(w6, bh(f6), fmaf(w7, bh(f7), a1))));
            e0 = g0; e1 = g1; e2 = g2; e3 = g3; e4 = g4; e5 = g5; e6 = g6; e7 = g7;
            f0 = c0; f1 = c1; f2 = c2; f3 = c3; f4 = c4; f5 = c5; f6 = c6; f7 = c7;
            sA = nA; sB = nB;
            rprev = rcur; rcur -= 8;
            ep += 8;
        }
        float w0 = wcalc(e0, erw, 0, rprev);
        float w1 = wcalc(e1, erw, 1, rprev);
        float w2 = wcalc(e2, erw, 2, rprev);
        float w3 = wcalc(e3, erw, 3, rprev);
        float w4 = wcalc(e4, erw, 4, rprev);
        float w5 = wcalc(e5, erw, 5, rprev);
        float w6 = wcalc(e6, erw, 6, rprev);
        float w7 = wcalc(e7, erw, 7, rprev);
        s += ((w0 + w1) + (w2 + w3)) + ((w4 + w5) + (w6 + w7));
        a0 = fmaf(w0, bl(f0), fmaf(w1, bl(f1), fmaf(w2, bl(f2), fmaf(w3, bl(f3), a0))));
        a0 = fmaf(w4, bl(f4), fmaf(w5, bl(f5), fmaf(w6, bl(f6), fmaf(w7, bl(f7), a0))));
        a1 = fmaf(w0, bh(f0), fmaf(w1, bh(f1), fmaf(w2, bh(f2), fmaf(w3, bh(f3), a1))));
        a1 = fmaf(w4, bh(f4), fmaf(w5, bh(f5), fmaf(w6, bh(f6), fmaf(w7, bh(f7), a1))));
    }
    float inv = (s > 0.f) ? fast_rcp(s) : 0.f;
    unsigned hv = *(const unsigned*)(h + (size_t)n * 128 + d0);
    float x0 = a0 * inv + bl(hv) + bias[d0];
    float x1 = a1 * inv + bh(hv) + bias[d0 + 1];
    x0 = (x0 > 0.f) ? x0 : expm1f(x0);              // elu
    x1 = (x1 > 0.f) ? x1 : expm1f(x1);
    unsigned outv = (unsigned)f2b(x0) | ((unsigned)f2b(x1) << 16);
    *(unsigned*)(h + (size_t)n * 128 + d0) = outv;
}

extern "C" void kernel_launch(void* const* d_in, const int* in_sizes, int n_in,
                              void* d_out, int out_size, void* d_ws, size_t ws_size,
                              hipStream_t stream) {
    const float* node_feats = (const float*)d_in[0];
    const int*   srcp       = (const int*)d_in[1];
    const int*   dstp       = (const int*)d_in[2];
    const float* proj_W     = (const float*)d_in[3];
    const float* proj_b     = (const float*)d_in[4];
    const float* fc_W       = (const float*)d_in[5];
    const float* attn_l     = (const float*)d_in[6];
    const float* attn_r     = (const float*)d_in[7];
    const float* conv_bias  = (const float*)d_in[8];
    const float* gru_Wih    = (const float*)d_in[9];
    // d_in[10] gru_Whh unused (h0 == 0)
    const float* gru_bih    = (const float*)d_in[11];
    const float* gru_bhh    = (const float*)d_in[12];
    float* outp = (float*)d_out;

    char* ws = (char*)d_ws;
    size_t off = 0;
    auto carve = [&](size_t bytes) -> char* {
        char* p = ws + off;
        off += (bytes + 255) & ~(size_t)255;
        return p;
    };
    // deg8, scan state, esrc carved adjacently -> single memset covers all three
    int*                deg8   = (int*)carve((size_t)8 * NNODES * 4);   // 1,280,000 B (mult of 256)
    unsigned long long* state  = (unsigned long long*)carve(512);       // 40 x 8B lookback state
    int*                esrc   = (int*)carve((size_t)(PADCAP + 32) * 4);
    int*                rowptr = (int*)carve((size_t)(NNODES + 1) * 4);
    int*                degt   = (int*)carve((size_t)NNODES * 4);
    int*                cur8   = (int*)carve((size_t)8 * NNODES * 4);
    float*              el     = (float*)carve((size_t)NNODES * 4 * 4);
    float*              er     = (float*)carve((size_t)NNODES * 4 * 4);
    unsigned short*     projWT = (unsigned short*)carve(16384 * 2);
    unsigned short*     fcWT   = (unsigned short*)carve(3 * 16384 * 2);
    unsigned short*     gruWb  = (unsigned short*)carve(49152 * 2);
    unsigned short*     h      = (unsigned short*)carve((size_t)M2PAD * 128 * 2);
    unsigned short*     feat   = (unsigned short*)carve((size_t)M2PAD * 128 * 2);
    (void)ws_size; (void)in_sizes; (void)n_in; (void)out_size;

    // single memset: deg8 + lookback state + esrc (pad slots gather node 0; weight 0 via deg)
    hipMemsetAsync(deg8, 0,
                   (size_t)8 * NNODES * 4 + 512 + (((size_t)(PADCAP + 32) * 4 + 255) & ~(size_t)255),
                   stream);
    prep_all<<<2948, 256, 0, stream>>>(proj_W, fc_W, gru_Wih, dstp,
                                       projWT, fcWT, gruWb, deg8);
    scan_lookback<<<40, 256, 0, stream>>>(deg8, rowptr, degt, cur8, state);

    // merged: CSR fill (atomic/scatter, latency-bound)  ||  proj + layer-0 fc gemm (MFMA)
    fill_proj<<<625 + NEDGES / 256, 256, 0, stream>>>(srcp, dstp, cur8, esrc,
                                                      node_feats, projWT, proj_b, fcWT, h, feat,
                                                      attn_l, attn_r, el, er);

    // 3 GAT layers (layer 0's gemm already fused above)
    for (int l = 0; l < 3; l++){
        if (l > 0){
            gemm_t<<<625, 256, 0, stream>>>(h, fcWT + l * 16384, feat,
                                            attn_l + l * 128, attn_r + l * 128, el, er);
        }
        aggregate<<<NNODES / 4, 256, 0, stream>>>(rowptr, degt, esrc, el, er, feat,
                                                  conv_bias + l * 128, h);
    }

    // fused double GRU step (de-staged: 16KB LDS, single barrier)
    gru2x<<<625, 256, 0, stream>>>(h, gruWb, gru_bih, gru_bhh, outp);
}

// Round 14
// 354.903 us; speedup vs baseline: 1.0171x; 1.0169x over previous
//
#include <hip/hip_runtime.h>
#include <hip/hip_bf16.h>

#define NNODES 40000
#define NEDGES 640000
#define M2PAD  40064
#define HID    128
#define PADCAP 920064                 // >= NEDGES + 7*NNODES, multiple of 256

typedef __attribute__((ext_vector_type(8))) short bf16x8;
typedef __attribute__((ext_vector_type(4))) float f32x4;

__device__ __forceinline__ float bl(unsigned u){ return __uint_as_float(u << 16); }
__device__ __forceinline__ float bh(unsigned u){ return __uint_as_float(u & 0xFFFF0000u); }
__device__ __forceinline__ unsigned short f2b(float f){
    unsigned u = __float_as_uint(f);
    u = (u + 0x7FFFu + ((u >> 16) & 1u)) >> 16;   // round-to-nearest-even
    return (unsigned short)u;
}
__device__ __forceinline__ float fast_rcp(float x){ return __builtin_amdgcn_rcpf(x); }

// edge weight: lrelu(el+er) -> exp, zero for pad slots (j >= remaining real edges)
__device__ __forceinline__ float wcalc(float e, float erw, int j, int rem){
    float t = e + erw;
    t = (t > 0.f) ? t : 0.2f * t;
    t = __expf(t);
    return (j < rem) ? t : 0.f;
}

// LDS byte offset for bf16 element (row, col) in the XOR-swizzled layout the
// MFMA fragment reader uses: chunk (col>>3) xor'd with (row&15), 2B within chunk.
__device__ __forceinline__ unsigned lds_off(int row, int col){
    return (unsigned)(row * 256 + (((col >> 3) ^ (row & 15)) << 4) + ((col & 7) << 1));
}

// ---------- prep: weight transpose (0..255) + gru cvt (256..447)
//            + degree count into 8 planes (448..2947) ----------
__global__ void prep_all(const float* __restrict__ proj_W, const float* __restrict__ fc_W,
                         const float* __restrict__ gru_Wih, const int* __restrict__ dstp,
                         unsigned short* __restrict__ projWT, unsigned short* __restrict__ fcWT,
                         unsigned short* __restrict__ gruWb, int* __restrict__ deg8){
    int b = blockIdx.x;
    if (b < 256){
        int c = b >> 6;                      // matrix 0..3
        int idx = (b & 63) * 256 + threadIdx.x;   // coalesced read
        const float* in   = (c == 0) ? proj_W : fc_W + (size_t)(c - 1) * 16384;
        unsigned short* o = (c == 0) ? projWT : fcWT + (size_t)(c - 1) * 16384;
        int k = idx >> 7, n = idx & 127;
        o[n * 128 + k] = f2b(in[idx]);       // scattered 2B write
    } else if (b < 448){
        int idx = (b - 256) * 256 + threadIdx.x;
        gruWb[idx] = f2b(gru_Wih[idx]);      // (384,128) already B^T layout
    } else {
        int e = (b - 448) * 256 + threadIdx.x;
        atomicAdd(&deg8[(e & 7) * NNODES + dstp[e]], 1);   // 8-plane: 8x less line contention
    }
}

// ---------- single-dispatch decoupled-lookback scan over 8-plane degrees ----------
__global__ __launch_bounds__(256) void scan_lookback(
        const int* __restrict__ deg8, int* __restrict__ rowptr, int* __restrict__ degt,
        int* __restrict__ cur8, unsigned long long* __restrict__ state){
    __shared__ int wincl[4];
    __shared__ int wexcl[4];
    __shared__ int blockT;
    __shared__ int baseSh;
    int b = blockIdx.x, t = threadIdx.x, lane = t & 63, wid = t >> 6;
    int i4 = b * 256 + t;
    bool ok = i4 < NNODES / 4;
    int4 d[8];
    #pragma unroll
    for (int x = 0; x < 8; x++)
        d[x] = ok ? ((const int4*)(deg8 + (size_t)x * NNODES))[i4] : make_int4(0, 0, 0, 0);
    int s0 = 0, s1 = 0, s2 = 0, s3 = 0;
    #pragma unroll
    for (int x = 0; x < 8; x++){ s0 += d[x].x; s1 += d[x].y; s2 += d[x].z; s3 += d[x].w; }
    int p0 = (s0 + 7) & ~7, p1 = (s1 + 7) & ~7;
    int p2 = (s2 + 7) & ~7, p3 = (s3 + 7) & ~7;
    int v = p0 + p1 + p2 + p3;
    int x = v;                                  // wave-inclusive scan
    #pragma unroll
    for (int dd = 1; dd < 64; dd <<= 1){
        int y = __shfl_up(x, dd, 64);
        if (lane >= dd) x += y;
    }
    if (lane == 63) wincl[wid] = x;
    __syncthreads();
    if (t == 0){
        int a = 0;
        #pragma unroll
        for (int i = 0; i < 4; i++){ wexcl[i] = a; a += wincl[i]; }
        blockT = a;
        __hip_atomic_store(&state[b], ((unsigned long long)(unsigned)a << 32) | 1ull,
                           __ATOMIC_RELEASE, __HIP_MEMORY_SCOPE_AGENT);
    }
    __syncthreads();
    // lookback: wave 0, lane i spins on predecessor i (< b); then 64-lane sum
    if (wid == 0){
        int contrib = 0;
        if (lane < b){
            unsigned long long st;
            do {
                st = __hip_atomic_load(&state[lane], __ATOMIC_ACQUIRE, __HIP_MEMORY_SCOPE_AGENT);
            } while (!(st & 1ull));
            contrib = (int)(st >> 32);
        }
        #pragma unroll
        for (int msk = 32; msk; msk >>= 1) contrib += __shfl_xor(contrib, msk, 64);
        if (lane == 0) baseSh = contrib;
    }
    __syncthreads();
    int base = baseSh;
    int excl = base + wexcl[wid] + (x - v);
    if (ok){
        int4 o = make_int4(excl, excl + p0, excl + p0 + p1, excl + p0 + p1 + p2);
        ((int4*)rowptr)[i4] = o;
        ((int4*)degt)[i4]   = make_int4(s0, s1, s2, s3);
        int o0 = o.x, o1 = o.y, o2 = o.z, o3 = o.w;
        #pragma unroll
        for (int xx = 0; xx < 8; xx++){
            ((int4*)(cur8 + (size_t)xx * NNODES))[i4] = make_int4(o0, o1, o2, o3);
            o0 += d[xx].x; o1 += d[xx].y; o2 += d[xx].z; o3 += d[xx].w;
        }
    }
    if (b == 39 && t == 0) rowptr[NNODES] = base + blockT;   // grand total
}

// ---------- merged dispatch: proj+fc0 gemm (blocks 0..624)  ||  CSR fill (blocks 625..3124)
// Phase A reads node_feats f32 DIRECT (cvt in-register); LDS (16KB) only for the
// phase A -> phase B handoff. B operands direct from L2-resident global.
__global__ __launch_bounds__(256) void fill_proj(
        const int* __restrict__ src, const int* __restrict__ dst,
        int* __restrict__ cur8, int* __restrict__ esrc,
        const float* __restrict__ node_feats,
        const unsigned short* __restrict__ projWT, const float* __restrict__ proj_b,
        const unsigned short* __restrict__ fcWT0,
        unsigned short* __restrict__ h, unsigned short* __restrict__ feat,
        const float* __restrict__ al, const float* __restrict__ ar,
        float* __restrict__ elp, float* __restrict__ erp)
{
    __shared__ unsigned char ldsA[16384];
    int b = blockIdx.x;
    if (b >= 625){
        // ---- fill path (no LDS use) ----
        int e = (b - 625) * 256 + threadIdx.x;
        int d = dst[e];
        int pos = atomicAdd(&cur8[(e & 7) * NNODES + d], 1);
        esrc[pos] = src[e];
        return;
    }
    // ---- proj + fc0 path ----
    int w = threadIdx.x >> 6, lane = threadIdx.x & 63;
    long baseM = (long)b * 64;                   // 625 * 64 == 40000 exactly
    int no = w * 32;
    int q = lane >> 4, cl = lane & 15;

    f32x4 acc[4][2];
    #pragma unroll
    for (int i = 0; i < 4; i++)
        #pragma unroll
        for (int j = 0; j < 2; j++) acc[i][j] = (f32x4){0.f, 0.f, 0.f, 0.f};

    // phase A: h_tile = nf_tile @ projWT  (A from f32 global w/ in-register cvt; B direct)
    #pragma unroll
    for (int kc = 0; kc < 4; kc++){
        int co = kc * 32 + q * 8;
        bf16x8 av[4], bv[2];
        #pragma unroll
        for (int mi = 0; mi < 4; mi++){
            const float* ap = node_feats + (baseM + mi * 16 + cl) * 128 + co;
            float4 x0 = *(const float4*)(ap);
            float4 x1 = *(const float4*)(ap + 4);
            bf16x8 t;
            t[0] = (short)f2b(x0.x); t[1] = (short)f2b(x0.y);
            t[2] = (short)f2b(x0.z); t[3] = (short)f2b(x0.w);
            t[4] = (short)f2b(x1.x); t[5] = (short)f2b(x1.y);
            t[6] = (short)f2b(x1.z); t[7] = (short)f2b(x1.w);
            av[mi] = t;
        }
        #pragma unroll
        for (int ni = 0; ni < 2; ni++)
            bv[ni] = *(const bf16x8*)(projWT + (no + ni * 16 + cl) * 128 + co);
        #pragma unroll
        for (int mi = 0; mi < 4; mi++)
            #pragma unroll
            for (int ni = 0; ni < 2; ni++)
                acc[mi][ni] = __builtin_amdgcn_mfma_f32_16x16x32_bf16(av[mi], bv[ni], acc[mi][ni], 0, 0, 0);
    }

    // epilogue A: h (global bf16) + deposit bf16 into ldsA (swizzled) for phase B
    #pragma unroll
    for (int ni = 0; ni < 2; ni++){
        int j = no + ni * 16 + cl;
        float bvf = proj_b[j];
        #pragma unroll
        for (int mi = 0; mi < 4; mi++){
            #pragma unroll
            for (int reg = 0; reg < 4; reg++){
                int row = mi * 16 + q * 4 + reg;
                unsigned short bb = f2b(acc[mi][ni][reg] + bvf);
                h[(baseM + row) * 128 + j] = bb;
                *(unsigned short*)(ldsA + lds_off(row, j)) = bb;
            }
        }
    }
    __syncthreads();   // handoff writes visible

    #pragma unroll
    for (int i = 0; i < 4; i++)
        #pragma unroll
        for (int j = 0; j < 2; j++) acc[i][j] = (f32x4){0.f, 0.f, 0.f, 0.f};

    // phase B: feat_tile = h_tile @ fcWT0  (A from LDS, B direct from global/L2)
    #pragma unroll
    for (int kc = 0; kc < 4; kc++){
        int co = kc * 32 + q * 8;
        bf16x8 av[4], bv[2];
        #pragma unroll
        for (int mi = 0; mi < 4; mi++){
            int row = mi * 16 + cl;
            int cs = (kc * 4 + q) ^ (row & 15);
            av[mi] = *(const bf16x8*)(ldsA + row * 256 + cs * 16);
        }
        #pragma unroll
        for (int ni = 0; ni < 2; ni++)
            bv[ni] = *(const bf16x8*)(fcWT0 + (no + ni * 16 + cl) * 128 + co);
        #pragma unroll
        for (int mi = 0; mi < 4; mi++)
            #pragma unroll
            for (int ni = 0; ni < 2; ni++)
                acc[mi][ni] = __builtin_amdgcn_mfma_f32_16x16x32_bf16(av[mi], bv[ni], acc[mi][ni], 0, 0, 0);
    }

    // epilogue B: feat (bf16) + fused el/er for layer 0
    #pragma unroll
    for (int mi = 0; mi < 4; mi++){
        #pragma unroll
        for (int ni = 0; ni < 2; ni++){
            int gn = no + ni * 16 + cl;
            #pragma unroll
            for (int reg = 0; reg < 4; reg++){
                long gm = baseM + mi * 16 + q * 4 + reg;
                feat[gm * 128 + gn] = f2b(acc[mi][ni][reg]);
            }
        }
    }
    float al_lo = al[no + cl], al_hi = al[no + 16 + cl];
    float ar_lo = ar[no + cl], ar_hi = ar[no + 16 + cl];
    #pragma unroll
    for (int mi = 0; mi < 4; mi++){
        #pragma unroll
        for (int reg = 0; reg < 4; reg++){
            float pl = acc[mi][0][reg] * al_lo + acc[mi][1][reg] * al_hi;
            float pr = acc[mi][0][reg] * ar_lo + acc[mi][1][reg] * ar_hi;
            #pragma unroll
            for (int msk = 8; msk; msk >>= 1){
                pl += __shfl_xor(pl, msk, 64);
                pr += __shfl_xor(pr, msk, 64);
            }
            long gm = baseM + mi * 16 + q * 4 + reg;
            if (cl == 0){
                elp[gm * 4 + w] = pl;
                erp[gm * 4 + w] = pr;
            }
        }
    }
}

// ---------- GEMM, fully de-staged (0 LDS): A/B fragments direct from global/L2 ----------
// 625 blocks x 64 rows; wave w covers cols w*32..w*32+31. Fused el/er.
__global__ __launch_bounds__(256) void gemm_t(
        const unsigned short* __restrict__ A, const unsigned short* __restrict__ BT,
        unsigned short* __restrict__ C,
        const float* __restrict__ al, const float* __restrict__ ar,
        float* __restrict__ elp, float* __restrict__ erp)
{
    int w = threadIdx.x >> 6, lane = threadIdx.x & 63;
    long baseM = (long)blockIdx.x * 64;
    int no = w * 32;
    int q = lane >> 4, cl = lane & 15;

    f32x4 acc[4][2];
    #pragma unroll
    for (int i = 0; i < 4; i++)
        #pragma unroll
        for (int j = 0; j < 2; j++) acc[i][j] = (f32x4){0.f, 0.f, 0.f, 0.f};

    #pragma unroll
    for (int kc = 0; kc < 4; kc++){
        int co = kc * 32 + q * 8;
        bf16x8 av[4], bv[2];
        #pragma unroll
        for (int mi = 0; mi < 4; mi++)
            av[mi] = *(const bf16x8*)(A + (baseM + mi * 16 + cl) * 128 + co);
        #pragma unroll
        for (int ni = 0; ni < 2; ni++)
            bv[ni] = *(const bf16x8*)(BT + (no + ni * 16 + cl) * 128 + co);
        #pragma unroll
        for (int mi = 0; mi < 4; mi++)
            #pragma unroll
            for (int ni = 0; ni < 2; ni++)
                acc[mi][ni] = __builtin_amdgcn_mfma_f32_16x16x32_bf16(av[mi], bv[ni], acc[mi][ni], 0, 0, 0);
    }

    // epilogue: C/D layout col=lane&15, row=(lane>>4)*4+reg   (625*64 == 40000 exactly)
    #pragma unroll
    for (int mi = 0; mi < 4; mi++){
        #pragma unroll
        for (int ni = 0; ni < 2; ni++){
            int gn = no + ni * 16 + cl;
            long gm0 = baseM + mi * 16 + q * 4;
            #pragma unroll
            for (int reg = 0; reg < 4; reg++)
                C[(gm0 + reg) * 128 + gn] = f2b(acc[mi][ni][reg]);
        }
    }

    // fused el/er: wave w == head w. 16-lane xor reduction over cl.
    float al_lo = al[no + cl], al_hi = al[no + 16 + cl];
    float ar_lo = ar[no + cl], ar_hi = ar[no + 16 + cl];
    #pragma unroll
    for (int mi = 0; mi < 4; mi++){
        #pragma unroll
        for (int reg = 0; reg < 4; reg++){
            float pl = acc[mi][0][reg] * al_lo + acc[mi][1][reg] * al_hi;
            float pr = acc[mi][0][reg] * ar_lo + acc[mi][1][reg] * ar_hi;
            #pragma unroll
            for (int msk = 8; msk; msk >>= 1){
                pl += __shfl_xor(pl, msk, 64);
                pr += __shfl_xor(pr, msk, 64);
            }
            long gm = baseM + mi * 16 + q * 4 + reg;
            if (cl == 0){
                elp[gm * 4 + w] = pl;
                erp[gm * 4 + w] = pr;
            }
        }
    }
}

// ---------- fused double GRU step, 32-row tiles for 2x TLP (1250 blocks) ----------
// B direct from L2-resident global; 8KB LDS for the step0->step1 handoff; 1 barrier.
__global__ __launch_bounds__(256) void gru2x(
        const unsigned short* __restrict__ A, const unsigned short* __restrict__ BT,
        const float* __restrict__ bih, const float* __restrict__ bhh,
        float* __restrict__ out)
{
    __shared__ unsigned char ldsA[8192];         // 32 rows x 256 B
    int w = threadIdx.x >> 6, lane = threadIdx.x & 63;
    long baseM = (long)blockIdx.x * 32;          // 1250 * 32 == 40000 exactly
    int no = w * 32;
    int q = lane >> 4, cl = lane & 15;

    #pragma unroll
    for (int s = 0; s < 2; s++){
        bf16x8 avall[4][2];               // [kc][mi]
        if (s == 0){
            #pragma unroll
            for (int kc = 0; kc < 4; kc++)
                #pragma unroll
                for (int mi = 0; mi < 2; mi++)
                    avall[kc][mi] = *(const bf16x8*)(A + (baseM + mi * 16 + cl) * 128 + kc * 32 + q * 8);
        } else {
            __syncthreads();              // s0 epilogue LDS writes visible
            #pragma unroll
            for (int kc = 0; kc < 4; kc++)
                #pragma unroll
                for (int mi = 0; mi < 2; mi++){
                    int row = mi * 16 + cl;
                    int cs = (kc * 4 + q) ^ (row & 15);
                    avall[kc][mi] = *(const bf16x8*)(ldsA + row * 256 + cs * 16);
                }
        }

        f32x4 acc[3][2][2];
        #pragma unroll
        for (int c = 0; c < 3; c++)
            #pragma unroll
            for (int i = 0; i < 2; i++)
                #pragma unroll
                for (int j = 0; j < 2; j++) acc[c][i][j] = (f32x4){0.f, 0.f, 0.f, 0.f};

        #pragma unroll
        for (int c = 0; c < 3; c++){
            #pragma unroll
            for (int kc = 0; kc < 4; kc++){
                bf16x8 bv[2];
                #pragma unroll
                for (int ni = 0; ni < 2; ni++)
                    bv[ni] = *(const bf16x8*)(BT + (c * 128 + no + ni * 16 + cl) * 128 + kc * 32 + q * 8);
                #pragma unroll
                for (int mi = 0; mi < 2; mi++)
                    #pragma unroll
                    for (int ni = 0; ni < 2; ni++)
                        acc[c][mi][ni] = __builtin_amdgcn_mfma_f32_16x16x32_bf16(avall[kc][mi], bv[ni], acc[c][mi][ni], 0, 0, 0);
            }
        }

        #pragma unroll
        for (int ni = 0; ni < 2; ni++){
            int j = no + ni * 16 + cl;
            float bir = bih[j]       + bhh[j];
            float biz = bih[128 + j] + bhh[128 + j];
            float bin = bih[256 + j];
            float bhn = bhh[256 + j];
            #pragma unroll
            for (int mi = 0; mi < 2; mi++){
                #pragma unroll
                for (int reg = 0; reg < 4; reg++){
                    int row = mi * 16 + q * 4 + reg;
                    float gr = acc[0][mi][ni][reg] + bir;
                    float gz = acc[1][mi][ni][reg] + biz;
                    float gn = acc[2][mi][ni][reg] + bin;
                    float r = fast_rcp(1.f + __expf(-gr));
                    float z = fast_rcp(1.f + __expf(-gz));
                    float ex = __expf(2.f * (gn + r * bhn));
                    float nn = (ex - 1.f) * fast_rcp(ex + 1.f);
                    float v = (1.f - z) * nn;
                    if (s == 0)
                        *(unsigned short*)(ldsA + lds_off(row, j)) = f2b(v);
                    else
                        out[(baseM + row) * 128 + j] = v;
                }
            }
        }
    }
}

// ---------- per-dst aggregation with fused edge weights ----------
__global__ __launch_bounds__(256) void aggregate(
        const int* __restrict__ rowptr, const int* __restrict__ degv,
        const int* __restrict__ esrc,
        const float* __restrict__ el, const float* __restrict__ er,
        const unsigned short* __restrict__ feat, const float* __restrict__ bias,
        unsigned short* __restrict__ h)
{
    int wid = threadIdx.x >> 6, lane = threadIdx.x & 63;
    int n = blockIdx.x * 4 + wid;
    int hh = lane >> 4;
    int d0 = lane * 2;
    unsigned doff = (unsigned)(d0 * 2);           // byte offset inside a feat row
    int beg = rowptr[n], end = rowptr[n + 1];
    int dg  = degv[n];
    float erw = er[(size_t)n * 4 + hh];
    float s = 0.f, a0 = 0.f, a1 = 0.f;
    const char* fbc = (const char*)feat;
    const int*  ep  = esrc + beg;

    if (beg < end){
        int4 sA = *(const int4*)(ep);
        int4 sB = *(const int4*)(ep + 4);
        float e0=0.f,e1=0.f,e2=0.f,e3=0.f,e4=0.f,e5=0.f,e6=0.f,e7=0.f;
        unsigned f0=0,f1=0,f2=0,f3=0,f4=0,f5=0,f6=0,f7=0;
        int rprev = 0;                // dummy group: all weights 0
        int rcur  = dg;
        for (int p = beg; p < end; p += 8){
            float g0 = el[(((unsigned)sA.x) << 2) + hh];
            float g1 = el[(((unsigned)sA.y) << 2) + hh];
            float g2 = el[(((unsigned)sA.z) << 2) + hh];
            float g3 = el[(((unsigned)sA.w) << 2) + hh];
            float g4 = el[(((unsigned)sB.x) << 2) + hh];
            float g5 = el[(((unsigned)sB.y) << 2) + hh];
            float g6 = el[(((unsigned)sB.z) << 2) + hh];
            float g7 = el[(((unsigned)sB.w) << 2) + hh];
            unsigned c0 = *(const unsigned*)(fbc + ((((unsigned)sA.x) << 8) + doff));
            unsigned c1 = *(const unsigned*)(fbc + ((((unsigned)sA.y) << 8) + doff));
            unsigned c2 = *(const unsigned*)(fbc + ((((unsigned)sA.z) << 8) + doff));
            unsigned c3 = *(const unsigned*)(fbc + ((((unsigned)sA.w) << 8) + doff));
            unsigned c4 = *(const unsigned*)(fbc + ((((unsigned)sB.x) << 8) + doff));
            unsigned c5 = *(const unsigned*)(fbc + ((((unsigned)sB.y) << 8) + doff));
            unsigned c6 = *(const unsigned*)(fbc + ((((unsigned)sB.z) << 8) + doff));
            unsigned c7 = *(const unsigned*)(fbc + ((((unsigned)sB.w) << 8) + doff));
            int4 nA = *(const int4*)(ep + 8);
            int4 nB = *(const int4*)(ep + 12);
            float w0 = wcalc(e0, erw, 0, rprev);
            float w1 = wcalc(e1, erw, 1, rprev);
            float w2 = wcalc(e2, erw, 2, rprev);
            float w3 = wcalc(e3, erw, 3, rprev);
            float w4 = wcalc(e4, erw, 4, rprev);
            float w5 = wcalc(e5, erw, 5, rprev);
            float w6 = wcalc(e6, erw, 6, rprev);
            float w7 = wcalc(e7, erw, 7, rprev);
            s += ((w0 + w1) + (w2 + w3)) + ((w4 + w5) + (w6 + w7));
            a0 = fmaf(w0, bl(f0), fmaf(w1, bl(f1), fmaf(w2, bl(f2), fmaf(w3, bl(f3), a0))));
            a0 = fmaf(w4, bl(f4), fmaf(w5, bl(f5), fmaf(w6, bl(f6), fmaf(w7, bl(f7), a0))));
            a1 = fmaf(w0, bh(f0), fmaf(w1, bh(f1), fmaf(w2, bh(f2), fmaf(w3, bh(f3), a1))));
            a1 = fmaf(w4, bh(f4), fmaf(w5, bh(f5), fmaf(w6, bh(f6), fmaf(w7, bh(f7), a1))));
            e0 = g0; e1 = g1; e2 = g2; e3 = g3; e4 = g4; e5 = g5; e6 = g6; e7 = g7;
            f0 = c0; f1 = c1; f2 = c2; f3 = c3; f4 = c4; f5 = c5; f6 = c6; f7 = c7;
            sA = nA; sB = nB;
            rprev = rcur; rcur -= 8;
            ep += 8;
        }
        float w0 = wcalc(e0, erw, 0, rprev);
        float w1 = wcalc(e1, erw, 1, rprev);
        float w2 = wcalc(e2, erw, 2, rprev);
        float w3 = wcalc(e3, erw, 3, rprev);
        float w4 = wcalc(e4, erw, 4, rprev);
        float w5 = wcalc(e5, erw, 5, rprev);
        float w6 = wcalc(e6, erw, 6, rprev);
        float w7 = wcalc(e7, erw, 7, rprev);
        s += ((w0 + w1) + (w2 + w3)) + ((w4 + w5) + (w6 + w7));
        a0 = fmaf(w0, bl(f0), fmaf(w1, bl(f1), fmaf(w2, bl(f2), fmaf(w3, bl(f3), a0))));
        a0 = fmaf(w4, bl(f4), fmaf(w5, bl(f5), fmaf(w6, bl(f6), fmaf(w7, bl(f7), a0))));
        a1 = fmaf(w0, bh(f0), fmaf(w1, bh(f1), fmaf(w2, bh(f2), fmaf(w3, bh(f3), a1))));
        a1 = fmaf(w4, bh(f4), fmaf(w5, bh(f5), fmaf(w6, bh(f6), fmaf(w7, bh(f7), a1))));
    }
    float inv = (s > 0.f) ? fast_rcp(s) : 0.f;
    unsigned hv = *(const unsigned*)(h + (size_t)n * 128 + d0);
    float x0 = a0 * inv + bl(hv) + bias[d0];
    float x1 = a1 * inv + bh(hv) + bias[d0 + 1];
    x0 = (x0 > 0.f) ? x0 : expm1f(x0);              // elu
    x1 = (x1 > 0.f) ? x1 : expm1f(x1);
    unsigned outv = (unsigned)f2b(x0) | ((unsigned)f2b(x1) << 16);
    *(unsigned*)(h + (size_t)n * 128 + d0) = outv;
}

extern "C" void kernel_launch(void* const* d_in, const int* in_sizes, int n_in,
                              void* d_out, int out_size, void* d_ws, size_t ws_size,
                              hipStream_t stream) {
    const float* node_feats = (const float*)d_in[0];
    const int*   srcp       = (const int*)d_in[1];
    const int*   dstp       = (const int*)d_in[2];
    const float* proj_W     = (const float*)d_in[3];
    const float* proj_b     = (const float*)d_in[4];
    const float* fc_W       = (const float*)d_in[5];
    const float* attn_l     = (const float*)d_in[6];
    const float* attn_r     = (const float*)d_in[7];
    const float* conv_bias  = (const float*)d_in[8];
    const float* gru_Wih    = (const float*)d_in[9];
    // d_in[10] gru_Whh unused (h0 == 0)
    const float* gru_bih    = (const float*)d_in[11];
    const float* gru_bhh    = (const float*)d_in[12];
    float* outp = (float*)d_out;

    char* ws = (char*)d_ws;
    size_t off = 0;
    auto carve = [&](size_t bytes) -> char* {
        char* p = ws + off;
        off += (bytes + 255) & ~(size_t)255;
        return p;
    };
    // deg8, scan state, esrc carved adjacently -> single memset covers all three
    int*                deg8   = (int*)carve((size_t)8 * NNODES * 4);   // 1,280,000 B (mult of 256)
    unsigned long long* state  = (unsigned long long*)carve(512);       // 40 x 8B lookback state
    int*                esrc   = (int*)carve((size_t)(PADCAP + 32) * 4);
    int*                rowptr = (int*)carve((size_t)(NNODES + 1) * 4);
    int*                degt   = (int*)carve((size_t)NNODES * 4);
    int*                cur8   = (int*)carve((size_t)8 * NNODES * 4);
    float*              el     = (float*)carve((size_t)NNODES * 4 * 4);
    float*              er     = (float*)carve((size_t)NNODES * 4 * 4);
    unsigned short*     projWT = (unsigned short*)carve(16384 * 2);
    unsigned short*     fcWT   = (unsigned short*)carve(3 * 16384 * 2);
    unsigned short*     gruWb  = (unsigned short*)carve(49152 * 2);
    unsigned short*     h      = (unsigned short*)carve((size_t)M2PAD * 128 * 2);
    unsigned short*     feat   = (unsigned short*)carve((size_t)M2PAD * 128 * 2);
    (void)ws_size; (void)in_sizes; (void)n_in; (void)out_size;

    // single memset: deg8 + lookback state + esrc (pad slots gather node 0; weight 0 via deg)
    hipMemsetAsync(deg8, 0,
                   (size_t)8 * NNODES * 4 + 512 + (((size_t)(PADCAP + 32) * 4 + 255) & ~(size_t)255),
                   stream);
    prep_all<<<2948, 256, 0, stream>>>(proj_W, fc_W, gru_Wih, dstp,
                                       projWT, fcWT, gruWb, deg8);
    scan_lookback<<<40, 256, 0, stream>>>(deg8, rowptr, degt, cur8, state);

    // merged: CSR fill (atomic/scatter, latency-bound)  ||  proj + layer-0 fc gemm (MFMA)
    fill_proj<<<625 + NEDGES / 256, 256, 0, stream>>>(srcp, dstp, cur8, esrc,
                                                      node_feats, projWT, proj_b, fcWT, h, feat,
                                                      attn_l, attn_r, el, er);

    // 3 GAT layers (layer 0's gemm already fused above)
    for (int l = 0; l < 3; l++){
        if (l > 0){
            gemm_t<<<625, 256, 0, stream>>>(h, fcWT + l * 16384, feat,
                                            attn_l + l * 128, attn_r + l * 128, el, er);
        }
        aggregate<<<NNODES / 4, 256, 0, stream>>>(rowptr, degt, esrc, el, er, feat,
                                                  conv_bias + l * 128, h);
    }

    // fused double GRU step (32-row tiles, 1250 blocks, 8KB LDS, single barrier)
    gru2x<<<1250, 256, 0, stream>>>(h, gruWb, gru_bih, gru_bhh, outp);
}

// Round 15
// 346.539 us; speedup vs baseline: 1.0416x; 1.0241x over previous
//
#include <hip/hip_runtime.h>
#include <hip/hip_bf16.h>

#define NNODES 40000
#define NEDGES 640000
#define M2PAD  40064
#define HID    128
#define PADCAP 920064                 // >= NEDGES + 7*NNODES, multiple of 256

typedef __attribute__((ext_vector_type(8))) short bf16x8;
typedef __attribute__((ext_vector_type(4))) float f32x4;

__device__ __forceinline__ float bl(unsigned u){ return __uint_as_float(u << 16); }
__device__ __forceinline__ float bh(unsigned u){ return __uint_as_float(u & 0xFFFF0000u); }
__device__ __forceinline__ unsigned short f2b(float f){
    unsigned u = __float_as_uint(f);
    u = (u + 0x7FFFu + ((u >> 16) & 1u)) >> 16;   // round-to-nearest-even
    return (unsigned short)u;
}
__device__ __forceinline__ float fast_rcp(float x){ return __builtin_amdgcn_rcpf(x); }

// edge weight: lrelu(el+er) -> exp, zero for pad slots (j >= remaining real edges)
__device__ __forceinline__ float wcalc(float e, float erw, int j, int rem){
    float t = e + erw;
    t = (t > 0.f) ? t : 0.2f * t;
    t = __expf(t);
    return (j < rem) ? t : 0.f;
}

// LDS byte offset for bf16 element (row, col) in the XOR-swizzled layout the
// MFMA fragment reader uses: chunk (col>>3) xor'd with (row&15), 2B within chunk.
__device__ __forceinline__ unsigned lds_off(int row, int col){
    return (unsigned)(row * 256 + (((col >> 3) ^ (row & 15)) << 4) + ((col & 7) << 1));
}

// ---------- prep: weight transpose (0..255) + gru cvt (256..447)
//            + degree count into 8 planes (448..2947) ----------
__global__ void prep_all(const float* __restrict__ proj_W, const float* __restrict__ fc_W,
                         const float* __restrict__ gru_Wih, const int* __restrict__ dstp,
                         unsigned short* __restrict__ projWT, unsigned short* __restrict__ fcWT,
                         unsigned short* __restrict__ gruWb, int* __restrict__ deg8){
    int b = blockIdx.x;
    if (b < 256){
        int c = b >> 6;                      // matrix 0..3
        int idx = (b & 63) * 256 + threadIdx.x;   // coalesced read
        const float* in   = (c == 0) ? proj_W : fc_W + (size_t)(c - 1) * 16384;
        unsigned short* o = (c == 0) ? projWT : fcWT + (size_t)(c - 1) * 16384;
        int k = idx >> 7, n = idx & 127;
        o[n * 128 + k] = f2b(in[idx]);       // scattered 2B write
    } else if (b < 448){
        int idx = (b - 256) * 256 + threadIdx.x;
        gruWb[idx] = f2b(gru_Wih[idx]);      // (384,128) already B^T layout
    } else {
        int e = (b - 448) * 256 + threadIdx.x;
        atomicAdd(&deg8[(e & 7) * NNODES + dstp[e]], 1);   // 8-plane: 8x less line contention
    }
}

// ---------- single-dispatch decoupled-lookback scan over 8-plane degrees ----------
__global__ __launch_bounds__(256) void scan_lookback(
        const int* __restrict__ deg8, int* __restrict__ rowptr, int* __restrict__ degt,
        int* __restrict__ cur8, unsigned long long* __restrict__ state){
    __shared__ int wincl[4];
    __shared__ int wexcl[4];
    __shared__ int blockT;
    __shared__ int baseSh;
    int b = blockIdx.x, t = threadIdx.x, lane = t & 63, wid = t >> 6;
    int i4 = b * 256 + t;
    bool ok = i4 < NNODES / 4;
    int4 d[8];
    #pragma unroll
    for (int x = 0; x < 8; x++)
        d[x] = ok ? ((const int4*)(deg8 + (size_t)x * NNODES))[i4] : make_int4(0, 0, 0, 0);
    int s0 = 0, s1 = 0, s2 = 0, s3 = 0;
    #pragma unroll
    for (int x = 0; x < 8; x++){ s0 += d[x].x; s1 += d[x].y; s2 += d[x].z; s3 += d[x].w; }
    int p0 = (s0 + 7) & ~7, p1 = (s1 + 7) & ~7;
    int p2 = (s2 + 7) & ~7, p3 = (s3 + 7) & ~7;
    int v = p0 + p1 + p2 + p3;
    int x = v;                                  // wave-inclusive scan
    #pragma unroll
    for (int dd = 1; dd < 64; dd <<= 1){
        int y = __shfl_up(x, dd, 64);
        if (lane >= dd) x += y;
    }
    if (lane == 63) wincl[wid] = x;
    __syncthreads();
    if (t == 0){
        int a = 0;
        #pragma unroll
        for (int i = 0; i < 4; i++){ wexcl[i] = a; a += wincl[i]; }
        blockT = a;
        __hip_atomic_store(&state[b], ((unsigned long long)(unsigned)a << 32) | 1ull,
                           __ATOMIC_RELEASE, __HIP_MEMORY_SCOPE_AGENT);
    }
    __syncthreads();
    // lookback: wave 0, lane i spins on predecessor i (< b); then 64-lane sum
    if (wid == 0){
        int contrib = 0;
        if (lane < b){
            unsigned long long st;
            do {
                st = __hip_atomic_load(&state[lane], __ATOMIC_ACQUIRE, __HIP_MEMORY_SCOPE_AGENT);
            } while (!(st & 1ull));
            contrib = (int)(st >> 32);
        }
        #pragma unroll
        for (int msk = 32; msk; msk >>= 1) contrib += __shfl_xor(contrib, msk, 64);
        if (lane == 0) baseSh = contrib;
    }
    __syncthreads();
    int base = baseSh;
    int excl = base + wexcl[wid] + (x - v);
    if (ok){
        int4 o = make_int4(excl, excl + p0, excl + p0 + p1, excl + p0 + p1 + p2);
        ((int4*)rowptr)[i4] = o;
        ((int4*)degt)[i4]   = make_int4(s0, s1, s2, s3);
        int o0 = o.x, o1 = o.y, o2 = o.z, o3 = o.w;
        #pragma unroll
        for (int xx = 0; xx < 8; xx++){
            ((int4*)(cur8 + (size_t)xx * NNODES))[i4] = make_int4(o0, o1, o2, o3);
            o0 += d[xx].x; o1 += d[xx].y; o2 += d[xx].z; o3 += d[xx].w;
        }
    }
    if (b == 39 && t == 0) rowptr[NNODES] = base + blockT;   // grand total
}

// ---------- merged dispatch, INTERLEAVED roles: proj if b%3==0 (625), fill else (1250).
// Interleaving co-schedules MFMA-heavy proj blocks with latency-bound fill blocks on
// every CU from the start (block-ordered dispatch previously ran them sequentially).
// Fill: 2 edges/thread for 2x memory-level parallelism.
__global__ __launch_bounds__(256) void fill_proj(
        const int* __restrict__ src, const int* __restrict__ dst,
        int* __restrict__ cur8, int* __restrict__ esrc,
        const float* __restrict__ node_feats,
        const unsigned short* __restrict__ projWT, const float* __restrict__ proj_b,
        const unsigned short* __restrict__ fcWT0,
        unsigned short* __restrict__ h, unsigned short* __restrict__ feat,
        const float* __restrict__ al, const float* __restrict__ ar,
        float* __restrict__ elp, float* __restrict__ erp)
{
    __shared__ unsigned char ldsA[16384];
    int b = blockIdx.x;                          // 1875 blocks total
    if (b % 3){
        // ---- fill path (no LDS): block fi of 1250, 512 edges, 2 per thread ----
        int fi = 2 * (b / 3) + (b % 3) - 1;
        int e0 = fi * 512 + threadIdx.x;
        int e1 = e0 + 256;
        int d0 = dst[e0], d1 = dst[e1];
        int s0 = src[e0], s1 = src[e1];
        int pos0 = atomicAdd(&cur8[(e0 & 7) * NNODES + d0], 1);
        int pos1 = atomicAdd(&cur8[(e1 & 7) * NNODES + d1], 1);
        esrc[pos0] = s0;
        esrc[pos1] = s1;
        return;
    }
    // ---- proj + fc0 path: block pi of 625 ----
    int pi = b / 3;
    int w = threadIdx.x >> 6, lane = threadIdx.x & 63;
    long baseM = (long)pi * 64;                  // 625 * 64 == 40000 exactly
    int no = w * 32;
    int q = lane >> 4, cl = lane & 15;

    f32x4 acc[4][2];
    #pragma unroll
    for (int i = 0; i < 4; i++)
        #pragma unroll
        for (int j = 0; j < 2; j++) acc[i][j] = (f32x4){0.f, 0.f, 0.f, 0.f};

    // phase A: h_tile = nf_tile @ projWT  (A from f32 global w/ in-register cvt; B direct)
    #pragma unroll
    for (int kc = 0; kc < 4; kc++){
        int co = kc * 32 + q * 8;
        bf16x8 av[4], bv[2];
        #pragma unroll
        for (int mi = 0; mi < 4; mi++){
            const float* ap = node_feats + (baseM + mi * 16 + cl) * 128 + co;
            float4 x0 = *(const float4*)(ap);
            float4 x1 = *(const float4*)(ap + 4);
            bf16x8 t;
            t[0] = (short)f2b(x0.x); t[1] = (short)f2b(x0.y);
            t[2] = (short)f2b(x0.z); t[3] = (short)f2b(x0.w);
            t[4] = (short)f2b(x1.x); t[5] = (short)f2b(x1.y);
            t[6] = (short)f2b(x1.z); t[7] = (short)f2b(x1.w);
            av[mi] = t;
        }
        #pragma unroll
        for (int ni = 0; ni < 2; ni++)
            bv[ni] = *(const bf16x8*)(projWT + (no + ni * 16 + cl) * 128 + co);
        #pragma unroll
        for (int mi = 0; mi < 4; mi++)
            #pragma unroll
            for (int ni = 0; ni < 2; ni++)
                acc[mi][ni] = __builtin_amdgcn_mfma_f32_16x16x32_bf16(av[mi], bv[ni], acc[mi][ni], 0, 0, 0);
    }

    // epilogue A: h (global bf16) + deposit bf16 into ldsA (swizzled) for phase B
    #pragma unroll
    for (int ni = 0; ni < 2; ni++){
        int j = no + ni * 16 + cl;
        float bvf = proj_b[j];
        #pragma unroll
        for (int mi = 0; mi < 4; mi++){
            #pragma unroll
            for (int reg = 0; reg < 4; reg++){
                int row = mi * 16 + q * 4 + reg;
                unsigned short bb = f2b(acc[mi][ni][reg] + bvf);
                h[(baseM + row) * 128 + j] = bb;
                *(unsigned short*)(ldsA + lds_off(row, j)) = bb;
            }
        }
    }
    __syncthreads();   // handoff writes visible

    #pragma unroll
    for (int i = 0; i < 4; i++)
        #pragma unroll
        for (int j = 0; j < 2; j++) acc[i][j] = (f32x4){0.f, 0.f, 0.f, 0.f};

    // phase B: feat_tile = h_tile @ fcWT0  (A from LDS, B direct from global/L2)
    #pragma unroll
    for (int kc = 0; kc < 4; kc++){
        int co = kc * 32 + q * 8;
        bf16x8 av[4], bv[2];
        #pragma unroll
        for (int mi = 0; mi < 4; mi++){
            int row = mi * 16 + cl;
            int cs = (kc * 4 + q) ^ (row & 15);
            av[mi] = *(const bf16x8*)(ldsA + row * 256 + cs * 16);
        }
        #pragma unroll
        for (int ni = 0; ni < 2; ni++)
            bv[ni] = *(const bf16x8*)(fcWT0 + (no + ni * 16 + cl) * 128 + co);
        #pragma unroll
        for (int mi = 0; mi < 4; mi++)
            #pragma unroll
            for (int ni = 0; ni < 2; ni++)
                acc[mi][ni] = __builtin_amdgcn_mfma_f32_16x16x32_bf16(av[mi], bv[ni], acc[mi][ni], 0, 0, 0);
    }

    // epilogue B: feat (bf16) + fused el/er for layer 0
    #pragma unroll
    for (int mi = 0; mi < 4; mi++){
        #pragma unroll
        for (int ni = 0; ni < 2; ni++){
            int gn = no + ni * 16 + cl;
            #pragma unroll
            for (int reg = 0; reg < 4; reg++){
                long gm = baseM + mi * 16 + q * 4 + reg;
                feat[gm * 128 + gn] = f2b(acc[mi][ni][reg]);
            }
        }
    }
    float al_lo = al[no + cl], al_hi = al[no + 16 + cl];
    float ar_lo = ar[no + cl], ar_hi = ar[no + 16 + cl];
    #pragma unroll
    for (int mi = 0; mi < 4; mi++){
        #pragma unroll
        for (int reg = 0; reg < 4; reg++){
            float pl = acc[mi][0][reg] * al_lo + acc[mi][1][reg] * al_hi;
            float pr = acc[mi][0][reg] * ar_lo + acc[mi][1][reg] * ar_hi;
            #pragma unroll
            for (int msk = 8; msk; msk >>= 1){
                pl += __shfl_xor(pl, msk, 64);
                pr += __shfl_xor(pr, msk, 64);
            }
            long gm = baseM + mi * 16 + q * 4 + reg;
            if (cl == 0){
                elp[gm * 4 + w] = pl;
                erp[gm * 4 + w] = pr;
            }
        }
    }
}

// ---------- GEMM, fully de-staged (0 LDS): A/B fragments direct from global/L2 ----------
// 625 blocks x 64 rows; wave w covers cols w*32..w*32+31. Fused el/er.
__global__ __launch_bounds__(256) void gemm_t(
        const unsigned short* __restrict__ A, const unsigned short* __restrict__ BT,
        unsigned short* __restrict__ C,
        const float* __restrict__ al, const float* __restrict__ ar,
        float* __restrict__ elp, float* __restrict__ erp)
{
    int w = threadIdx.x >> 6, lane = threadIdx.x & 63;
    long baseM = (long)blockIdx.x * 64;
    int no = w * 32;
    int q = lane >> 4, cl = lane & 15;

    f32x4 acc[4][2];
    #pragma unroll
    for (int i = 0; i < 4; i++)
        #pragma unroll
        for (int j = 0; j < 2; j++) acc[i][j] = (f32x4){0.f, 0.f, 0.f, 0.f};

    #pragma unroll
    for (int kc = 0; kc < 4; kc++){
        int co = kc * 32 + q * 8;
        bf16x8 av[4], bv[2];
        #pragma unroll
        for (int mi = 0; mi < 4; mi++)
            av[mi] = *(const bf16x8*)(A + (baseM + mi * 16 + cl) * 128 + co);
        #pragma unroll
        for (int ni = 0; ni < 2; ni++)
            bv[ni] = *(const bf16x8*)(BT + (no + ni * 16 + cl) * 128 + co);
        #pragma unroll
        for (int mi = 0; mi < 4; mi++)
            #pragma unroll
            for (int ni = 0; ni < 2; ni++)
                acc[mi][ni] = __builtin_amdgcn_mfma_f32_16x16x32_bf16(av[mi], bv[ni], acc[mi][ni], 0, 0, 0);
    }

    // epilogue: C/D layout col=lane&15, row=(lane>>4)*4+reg   (625*64 == 40000 exactly)
    #pragma unroll
    for (int mi = 0; mi < 4; mi++){
        #pragma unroll
        for (int ni = 0; ni < 2; ni++){
            int gn = no + ni * 16 + cl;
            long gm0 = baseM + mi * 16 + q * 4;
            #pragma unroll
            for (int reg = 0; reg < 4; reg++)
                C[(gm0 + reg) * 128 + gn] = f2b(acc[mi][ni][reg]);
        }
    }

    // fused el/er: wave w == head w. 16-lane xor reduction over cl.
    float al_lo = al[no + cl], al_hi = al[no + 16 + cl];
    float ar_lo = ar[no + cl], ar_hi = ar[no + 16 + cl];
    #pragma unroll
    for (int mi = 0; mi < 4; mi++){
        #pragma unroll
        for (int reg = 0; reg < 4; reg++){
            float pl = acc[mi][0][reg] * al_lo + acc[mi][1][reg] * al_hi;
            float pr = acc[mi][0][reg] * ar_lo + acc[mi][1][reg] * ar_hi;
            #pragma unroll
            for (int msk = 8; msk; msk >>= 1){
                pl += __shfl_xor(pl, msk, 64);
                pr += __shfl_xor(pr, msk, 64);
            }
            long gm = baseM + mi * 16 + q * 4 + reg;
            if (cl == 0){
                elp[gm * 4 + w] = pl;
                erp[gm * 4 + w] = pr;
            }
        }
    }
}

// ---------- fused double GRU step, 32-row tiles for 2x TLP (1250 blocks) ----------
// B direct from L2-resident global; 8KB LDS for the step0->step1 handoff; 1 barrier.
__global__ __launch_bounds__(256) void gru2x(
        const unsigned short* __restrict__ A, const unsigned short* __restrict__ BT,
        const float* __restrict__ bih, const float* __restrict__ bhh,
        float* __restrict__ out)
{
    __shared__ unsigned char ldsA[8192];         // 32 rows x 256 B
    int w = threadIdx.x >> 6, lane = threadIdx.x & 63;
    long baseM = (long)blockIdx.x * 32;          // 1250 * 32 == 40000 exactly
    int no = w * 32;
    int q = lane >> 4, cl = lane & 15;

    #pragma unroll
    for (int s = 0; s < 2; s++){
        bf16x8 avall[4][2];               // [kc][mi]
        if (s == 0){
            #pragma unroll
            for (int kc = 0; kc < 4; kc++)
                #pragma unroll
                for (int mi = 0; mi < 2; mi++)
                    avall[kc][mi] = *(const bf16x8*)(A + (baseM + mi * 16 + cl) * 128 + kc * 32 + q * 8);
        } else {
            __syncthreads();              // s0 epilogue LDS writes visible
            #pragma unroll
            for (int kc = 0; kc < 4; kc++)
                #pragma unroll
                for (int mi = 0; mi < 2; mi++){
                    int row = mi * 16 + cl;
                    int cs = (kc * 4 + q) ^ (row & 15);
                    avall[kc][mi] = *(const bf16x8*)(ldsA + row * 256 + cs * 16);
                }
        }

        f32x4 acc[3][2][2];
        #pragma unroll
        for (int c = 0; c < 3; c++)
            #pragma unroll
            for (int i = 0; i < 2; i++)
                #pragma unroll
                for (int j = 0; j < 2; j++) acc[c][i][j] = (f32x4){0.f, 0.f, 0.f, 0.f};

        #pragma unroll
        for (int c = 0; c < 3; c++){
            #pragma unroll
            for (int kc = 0; kc < 4; kc++){
                bf16x8 bv[2];
                #pragma unroll
                for (int ni = 0; ni < 2; ni++)
                    bv[ni] = *(const bf16x8*)(BT + (c * 128 + no + ni * 16 + cl) * 128 + kc * 32 + q * 8);
                #pragma unroll
                for (int mi = 0; mi < 2; mi++)
                    #pragma unroll
                    for (int ni = 0; ni < 2; ni++)
                        acc[c][mi][ni] = __builtin_amdgcn_mfma_f32_16x16x32_bf16(avall[kc][mi], bv[ni], acc[c][mi][ni], 0, 0, 0);
            }
        }

        #pragma unroll
        for (int ni = 0; ni < 2; ni++){
            int j = no + ni * 16 + cl;
            float bir = bih[j]       + bhh[j];
            float biz = bih[128 + j] + bhh[128 + j];
            float bin = bih[256 + j];
            float bhn = bhh[256 + j];
            #pragma unroll
            for (int mi = 0; mi < 2; mi++){
                #pragma unroll
                for (int reg = 0; reg < 4; reg++){
                    int row = mi * 16 + q * 4 + reg;
                    float gr = acc[0][mi][ni][reg] + bir;
                    float gz = acc[1][mi][ni][reg] + biz;
                    float gn = acc[2][mi][ni][reg] + bin;
                    float r = fast_rcp(1.f + __expf(-gr));
                    float z = fast_rcp(1.f + __expf(-gz));
                    float ex = __expf(2.f * (gn + r * bhn));
                    float nn = (ex - 1.f) * fast_rcp(ex + 1.f);
                    float v = (1.f - z) * nn;
                    if (s == 0)
                        *(unsigned short*)(ldsA + lds_off(row, j)) = f2b(v);
                    else
                        out[(baseM + row) * 128 + j] = v;
                }
            }
        }
    }
}

// ---------- per-dst aggregation with fused edge weights ----------
__global__ __launch_bounds__(256) void aggregate(
        const int* __restrict__ rowptr, const int* __restrict__ degv,
        const int* __restrict__ esrc,
        const float* __restrict__ el, const float* __restrict__ er,
        const unsigned short* __restrict__ feat, const float* __restrict__ bias,
        unsigned short* __restrict__ h)
{
    int wid = threadIdx.x >> 6, lane = threadIdx.x & 63;
    int n = blockIdx.x * 4 + wid;
    int hh = lane >> 4;
    int d0 = lane * 2;
    unsigned doff = (unsigned)(d0 * 2);           // byte offset inside a feat row
    int beg = rowptr[n], end = rowptr[n + 1];
    int dg  = degv[n];
    float erw = er[(size_t)n * 4 + hh];
    float s = 0.f, a0 = 0.f, a1 = 0.f;
    const char* fbc = (const char*)feat;
    const int*  ep  = esrc + beg;

    if (beg < end){
        int4 sA = *(const int4*)(ep);
        int4 sB = *(const int4*)(ep + 4);
        float e0=0.f,e1=0.f,e2=0.f,e3=0.f,e4=0.f,e5=0.f,e6=0.f,e7=0.f;
        unsigned f0=0,f1=0,f2=0,f3=0,f4=0,f5=0,f6=0,f7=0;
        int rprev = 0;                // dummy group: all weights 0
        int rcur  = dg;
        for (int p = beg; p < end; p += 8){
            float g0 = el[(((unsigned)sA.x) << 2) + hh];
            float g1 = el[(((unsigned)sA.y) << 2) + hh];
            float g2 = el[(((unsigned)sA.z) << 2) + hh];
            float g3 = el[(((unsigned)sA.w) << 2) + hh];
            float g4 = el[(((unsigned)sB.x) << 2) + hh];
            float g5 = el[(((unsigned)sB.y) << 2) + hh];
            float g6 = el[(((unsigned)sB.z) << 2) + hh];
            float g7 = el[(((unsigned)sB.w) << 2) + hh];
            unsigned c0 = *(const unsigned*)(fbc + ((((unsigned)sA.x) << 8) + doff));
            unsigned c1 = *(const unsigned*)(fbc + ((((unsigned)sA.y) << 8) + doff));
            unsigned c2 = *(const unsigned*)(fbc + ((((unsigned)sA.z) << 8) + doff));
            unsigned c3 = *(const unsigned*)(fbc + ((((unsigned)sA.w) << 8) + doff));
            unsigned c4 = *(const unsigned*)(fbc + ((((unsigned)sB.x) << 8) + doff));
            unsigned c5 = *(const unsigned*)(fbc + ((((unsigned)sB.y) << 8) + doff));
            unsigned c6 = *(const unsigned*)(fbc + ((((unsigned)sB.z) << 8) + doff));
            unsigned c7 = *(const unsigned*)(fbc + ((((unsigned)sB.w) << 8) + doff));
            int4 nA = *(const int4*)(ep + 8);
            int4 nB = *(const int4*)(ep + 12);
            float w0 = wcalc(e0, erw, 0, rprev);
            float w1 = wcalc(e1, erw, 1, rprev);
            float w2 = wcalc(e2, erw, 2, rprev);
            float w3 = wcalc(e3, erw, 3, rprev);
            float w4 = wcalc(e4, erw, 4, rprev);
            float w5 = wcalc(e5, erw, 5, rprev);
            float w6 = wcalc(e6, erw, 6, rprev);
            float w7 = wcalc(e7, erw, 7, rprev);
            s += ((w0 + w1) + (w2 + w3)) + ((w4 + w5) + (w6 + w7));
            a0 = fmaf(w0, bl(f0), fmaf(w1, bl(f1), fmaf(w2, bl(f2), fmaf(w3, bl(f3), a0))));
            a0 = fmaf(w4, bl(f4), fmaf(w5, bl(f5), fmaf(w6, bl(f6), fmaf(w7, bl(f7), a0))));
            a1 = fmaf(w0, bh(f0), fmaf(w1, bh(f1), fmaf(w2, bh(f2), fmaf(w3, bh(f3), a1))));
            a1 = fmaf(w4, bh(f4), fmaf(w5, bh(f5), fmaf(w6, bh(f6), fmaf(w7, bh(f7), a1))));
            e0 = g0; e1 = g1; e2 = g2; e3 = g3; e4 = g4; e5 = g5; e6 = g6; e7 = g7;
            f0 = c0; f1 = c1; f2 = c2; f3 = c3; f4 = c4; f5 = c5; f6 = c6; f7 = c7;
            sA = nA; sB = nB;
            rprev = rcur; rcur -= 8;
            ep += 8;
        }
        float w0 = wcalc(e0, erw, 0, rprev);
        float w1 = wcalc(e1, erw, 1, rprev);
        float w2 = wcalc(e2, erw, 2, rprev);
        float w3 = wcalc(e3, erw, 3, rprev);
        float w4 = wcalc(e4, erw, 4, rprev);
        float w5 = wcalc(e5, erw, 5, rprev);
        float w6 = wcalc(e6, erw, 6, rprev);
        float w7 = wcalc(e7, erw, 7, rprev);
        s += ((w0 + w1) + (w2 + w3)) + ((w4 + w5) + (w6 + w7));
        a0 = fmaf(w0, bl(f0), fmaf(w1, bl(f1), fmaf(w2, bl(f2), fmaf(w3, bl(f3), a0))));
        a0 = fmaf(w4, bl(f4), fmaf(w5, bl(f5), fmaf(w6, bl(f6), fmaf(w7, bl(f7), a0))));
        a1 = fmaf(w0, bh(f0), fmaf(w1, bh(f1), fmaf(w2, bh(f2), fmaf(w3, bh(f3), a1))));
        a1 = fmaf(w4, bh(f4), fmaf(w5, bh(f5), fmaf(w6, bh(f6), fmaf(w7, bh(f7), a1))));
    }
    float inv = (s > 0.f) ? fast_rcp(s) : 0.f;
    unsigned hv = *(const unsigned*)(h + (size_t)n * 128 + d0);
    float x0 = a0 * inv + bl(hv) + bias[d0];
    float x1 = a1 * inv + bh(hv) + bias[d0 + 1];
    x0 = (x0 > 0.f) ? x0 : expm1f(x0);              // elu
    x1 = (x1 > 0.f) ? x1 : expm1f(x1);
    unsigned outv = (unsigned)f2b(x0) | ((unsigned)f2b(x1) << 16);
    *(unsigned*)(h + (size_t)n * 128 + d0) = outv;
}

extern "C" void kernel_launch(void* const* d_in, const int* in_sizes, int n_in,
                              void* d_out, int out_size, void* d_ws, size_t ws_size,
                              hipStream_t stream) {
    const float* node_feats = (const float*)d_in[0];
    const int*   srcp       = (const int*)d_in[1];
    const int*   dstp       = (const int*)d_in[2];
    const float* proj_W     = (const float*)d_in[3];
    const float* proj_b     = (const float*)d_in[4];
    const float* fc_W       = (const float*)d_in[5];
    const float* attn_l     = (const float*)d_in[6];
    const float* attn_r     = (const float*)d_in[7];
    const float* conv_bias  = (const float*)d_in[8];
    const float* gru_Wih    = (const float*)d_in[9];
    // d_in[10] gru_Whh unused (h0 == 0)
    const float* gru_bih    = (const float*)d_in[11];
    const float* gru_bhh    = (const float*)d_in[12];
    float* outp = (float*)d_out;

    char* ws = (char*)d_ws;
    size_t off = 0;
    auto carve = [&](size_t bytes) -> char* {
        char* p = ws + off;
        off += (bytes + 255) & ~(size_t)255;
        return p;
    };
    // deg8, scan state, esrc carved adjacently -> single memset covers all three
    int*                deg8   = (int*)carve((size_t)8 * NNODES * 4);   // 1,280,000 B (mult of 256)
    unsigned long long* state  = (unsigned long long*)carve(512);       // 40 x 8B lookback state
    int*                esrc   = (int*)carve((size_t)(PADCAP + 32) * 4);
    int*                rowptr = (int*)carve((size_t)(NNODES + 1) * 4);
    int*                degt   = (int*)carve((size_t)NNODES * 4);
    int*                cur8   = (int*)carve((size_t)8 * NNODES * 4);
    float*              el     = (float*)carve((size_t)NNODES * 4 * 4);
    float*              er     = (float*)carve((size_t)NNODES * 4 * 4);
    unsigned short*     projWT = (unsigned short*)carve(16384 * 2);
    unsigned short*     fcWT   = (unsigned short*)carve(3 * 16384 * 2);
    unsigned short*     gruWb  = (unsigned short*)carve(49152 * 2);
    unsigned short*     h      = (unsigned short*)carve((size_t)M2PAD * 128 * 2);
    unsigned short*     feat   = (unsigned short*)carve((size_t)M2PAD * 128 * 2);
    (void)ws_size; (void)in_sizes; (void)n_in; (void)out_size;

    // single memset: deg8 + lookback state + esrc (pad slots gather node 0; weight 0 via deg)
    hipMemsetAsync(deg8, 0,
                   (size_t)8 * NNODES * 4 + 512 + (((size_t)(PADCAP + 32) * 4 + 255) & ~(size_t)255),
                   stream);
    prep_all<<<2948, 256, 0, stream>>>(proj_W, fc_W, gru_Wih, dstp,
                                       projWT, fcWT, gruWb, deg8);
    scan_lookback<<<40, 256, 0, stream>>>(deg8, rowptr, degt, cur8, state);

    // merged, role-interleaved: CSR fill (2 edges/thread)  ||  proj + layer-0 fc gemm
    fill_proj<<<1875, 256, 0, stream>>>(srcp, dstp, cur8, esrc,
                                        node_feats, projWT, proj_b, fcWT, h, feat,
                                        attn_l, attn_r, el, er);

    // 3 GAT layers (layer 0's gemm already fused above)
    for (int l = 0; l < 3; l++){
        if (l > 0){
            gemm_t<<<625, 256, 0, stream>>>(h, fcWT + l * 16384, feat,
                                            attn_l + l * 128, attn_r + l * 128, el, er);
        }
        aggregate<<<NNODES / 4, 256, 0, stream>>>(rowptr, degt, esrc, el, er, feat,
                                                  conv_bias + l * 128, h);
    }

    // fused double GRU step (32-row tiles, 1250 blocks, 8KB LDS, single barrier)
    gru2x<<<1250, 256, 0, stream>>>(h, gruWb, gru_bih, gru_bhh, outp);
}